// Round 4
// baseline (570.283 us; speedup 1.0000x reference)
//
#include <hip/hip_runtime.h>

// ---------------- common helpers ----------------
using bf16x8 = __attribute__((ext_vector_type(8))) short;
using f32x4  = __attribute__((ext_vector_type(4))) float;

#define DEV __device__ __forceinline__

DEV short f2bf(float x){
  unsigned u = __float_as_uint(x);
  u += 0x7fffu + ((u >> 16) & 1u);
  return (short)(u >> 16);
}
DEV float bf2f(short h){ return __uint_as_float(((unsigned)(unsigned short)h) << 16); }

#define MFMA16(a,b,c) __builtin_amdgcn_mfma_f32_16x16x32_bf16(a,b,c,0,0,0)

// async global->LDS, 16B per lane; LDS dest is wave-uniform base + lane*16
DEV void gl_lds16(const void* g, void* l){
  __builtin_amdgcn_global_load_lds(
      (const __attribute__((address_space(1))) unsigned*)g,
      (__attribute__((address_space(3))) unsigned*)l, 16, 0, 0);
}

// Problem constants: B=2 S=1024 D=768 H=12 HD=64 E=8 DF=3072 K=2, T=2048

// ---------------- transpose + fp32->bf16(hi/lo) convert ----------------
__global__ void k_transpose(const float* __restrict__ src, long sbatch,
                            short* __restrict__ dhi, short* __restrict__ dlo, long dbatch,
                            int R, int C){
  __shared__ float tile[32][33];
  const float* s = src + (long)blockIdx.z * sbatch;
  int c0 = blockIdx.x * 32, r0 = blockIdx.y * 32;
  int tx = threadIdx.x & 31, ty = threadIdx.x >> 5;   // 32x8
  #pragma unroll
  for (int i = 0; i < 4; i++)
    tile[ty + 8*i][tx] = s[(long)(r0 + ty + 8*i) * C + c0 + tx];
  __syncthreads();
  #pragma unroll
  for (int i = 0; i < 4; i++){
    int c = c0 + ty + 8*i;
    float v = tile[tx][ty + 8*i];
    short hv = f2bf(v);
    long o = (long)blockIdx.z * dbatch + (long)c * R + r0 + tx;
    dhi[o] = hv;
    if (dlo) dlo[o] = f2bf(v - bf2f(hv));
  }
}

// ---------------- LayerNorm1: x -> xn1 hi/lo bf16 ----------------
__global__ void k_ln1(const float* __restrict__ x, const float* __restrict__ g,
                      const float* __restrict__ bb,
                      short* __restrict__ xh, short* __restrict__ xl){
  int t = blockIdx.x, tid = threadIdx.x;
  const float* xr = x + (long)t * 768;
  float v[3];
  #pragma unroll
  for (int j = 0; j < 3; j++) v[j] = xr[tid + 256*j];
  float s = v[0]+v[1]+v[2];
  float q = v[0]*v[0]+v[1]*v[1]+v[2]*v[2];
  #pragma unroll
  for (int o = 32; o > 0; o >>= 1){ s += __shfl_down(s,o,64); q += __shfl_down(q,o,64); }
  __shared__ float ss[4], qs[4];
  int w = tid >> 6;
  if ((tid & 63) == 0){ ss[w] = s; qs[w] = q; }
  __syncthreads();
  float St = ss[0]+ss[1]+ss[2]+ss[3], Qt = qs[0]+qs[1]+qs[2]+qs[3];
  float mean = St * (1.f/768.f);
  float var  = Qt * (1.f/768.f) - mean*mean;
  float inv  = 1.f / sqrtf(var + 1e-5f);
  #pragma unroll
  for (int j = 0; j < 3; j++){
    int d = tid + 256*j;
    float xn = (v[j]-mean)*inv*g[d] + bb[d];
    short hv = f2bf(xn);
    xh[(long)t*768 + d] = hv;
    xl[(long)t*768 + d] = f2bf(xn - bf2f(hv));
  }
}

// ---------------- split-bf16 GEMM: qkv = xn1 @ Wqkv (gl_lds staging) --------
__global__ __launch_bounds__(256,2) void k_qkv(
    const short* __restrict__ Ah, const short* __restrict__ Al,
    const short* __restrict__ Bh, const short* __restrict__ Bl,
    short* __restrict__ qh, short* __restrict__ ql,
    short* __restrict__ kh, short* __restrict__ kl,
    short* __restrict__ vh, short* __restrict__ vl){
  int M0 = blockIdx.x * 128, N0 = blockIdx.y * 128;
  __shared__ __align__(16) short lah[128*32], lal[128*32], lbh[128*32], lbl[128*32];
  int tid = threadIdx.x;
  int w = tid >> 6, lane = tid & 63, l15 = lane & 15, quad = lane >> 4;
  int mbase = (w & 1) * 64, nbase = (w >> 1) * 64;
  f32x4 acc[4][4];
  #pragma unroll
  for (int i = 0; i < 4; i++)
    #pragma unroll
    for (int j = 0; j < 4; j++) acc[i][j] = (f32x4){0.f,0.f,0.f,0.f};
  int sr = w*32 + (lane >> 2);
  int sc = ((lane & 3) ^ (sr & 3)) * 8;
  long gA = (long)(M0 + sr)*768 + sc;
  long gB = (long)(N0 + sr)*768 + sc;
  int swq = (quad ^ (l15 & 3)) * 8;
  for (int k0 = 0; k0 < 768; k0 += 32){
    gl_lds16(Ah + gA + k0,          lah + w*1024);
    gl_lds16(Ah + gA + 16*768 + k0, lah + w*1024 + 512);
    gl_lds16(Al + gA + k0,          lal + w*1024);
    gl_lds16(Al + gA + 16*768 + k0, lal + w*1024 + 512);
    gl_lds16(Bh + gB + k0,          lbh + w*1024);
    gl_lds16(Bh + gB + 16*768 + k0, lbh + w*1024 + 512);
    gl_lds16(Bl + gB + k0,          lbl + w*1024);
    gl_lds16(Bl + gB + 16*768 + k0, lbl + w*1024 + 512);
    __syncthreads();
    bf16x8 afh[4], afl[4];
    #pragma unroll
    for (int mt = 0; mt < 4; mt++){
      afh[mt] = *(const bf16x8*)&lah[(mbase+mt*16+l15)*32 + swq];
      afl[mt] = *(const bf16x8*)&lal[(mbase+mt*16+l15)*32 + swq];
    }
    #pragma unroll
    for (int nt = 0; nt < 4; nt++){
      bf16x8 bfh = *(const bf16x8*)&lbh[(nbase+nt*16+l15)*32 + swq];
      bf16x8 bfl = *(const bf16x8*)&lbl[(nbase+nt*16+l15)*32 + swq];
      #pragma unroll
      for (int mt = 0; mt < 4; mt++){
        acc[mt][nt] = MFMA16(afh[mt], bfh, acc[mt][nt]);
        acc[mt][nt] = MFMA16(afh[mt], bfl, acc[mt][nt]);
        acc[mt][nt] = MFMA16(afl[mt], bfh, acc[mt][nt]);
      }
    }
    __syncthreads();
  }
  // epilogue: scatter into q[bh][s][hd], k[bh][s][hd], vT[bh][hd][s]
  #pragma unroll
  for (int mt = 0; mt < 4; mt++){
    #pragma unroll
    for (int nt = 0; nt < 4; nt++){
      #pragma unroll
      for (int rg = 0; rg < 4; rg++){
        int m = M0 + mbase + mt*16 + quad*4 + rg;
        int n = N0 + nbase + nt*16 + l15;
        float vv = acc[mt][nt][rg];
        int bi = m >> 10, si = m & 1023;
        if (n < 768){
          float sv = vv * 0.125f;              // fold 1/sqrt(HD)
          short hv = f2bf(sv);
          int hh = n >> 6, hd = n & 63;
          long o = (((long)(bi*12+hh)*1024) + si)*64 + hd;
          qh[o] = hv; ql[o] = f2bf(sv - bf2f(hv));
        } else if (n < 1536){
          int n2 = n - 768;
          short hv = f2bf(vv);
          int hh = n2 >> 6, hd = n2 & 63;
          long o = (((long)(bi*12+hh)*1024) + si)*64 + hd;
          kh[o] = hv; kl[o] = f2bf(vv - bf2f(hv));
        } else {
          int n2 = n - 1536;
          short hv = f2bf(vv);
          int hh = n2 >> 6, hd = n2 & 63;
          long o = (((long)(bi*12+hh)*64) + hd)*1024 + si;
          vh[o] = hv; vl[o] = f2bf(vv - bf2f(hv));
        }
      }
    }
  }
}

// ---------------- flash attention, split-bf16, causal, split-K=2 ------------
__global__ __launch_bounds__(256,3) void k_attn(
    const short* __restrict__ qh, const short* __restrict__ ql,
    const short* __restrict__ kh, const short* __restrict__ kl,
    const short* __restrict__ vth, const short* __restrict__ vtl,
    float* __restrict__ po, float* __restrict__ pm, float* __restrict__ pl){
  int qt = blockIdx.x >> 1, half = blockIdx.x & 1, bh = blockIdx.y;
  int q0 = qt * 64;
  long base = (long)bh * 1024 * 64;
  int ktb = half ? ((qt + 2) >> 1) : 0;
  int kte = half ? (qt + 1) : ((qt + 2) >> 1);
  __shared__ __align__(16) short skh[64*64], skl[64*64], svh[64*64], svl[64*64];
  __shared__ __align__(16) short sph[4][16*72], spl[4][16*72];
  int tid = threadIdx.x, w = tid >> 6, lane = tid & 63, l15 = lane & 15, quad = lane >> 4;
  bf16x8 qfh[2], qfl[2];
  #pragma unroll
  for (int c = 0; c < 2; c++){
    long qa = base + (long)(q0 + w*16 + l15)*64 + c*32 + quad*8;
    qfh[c] = *(const bf16x8*)(qh + qa);
    qfl[c] = *(const bf16x8*)(ql + qa);
  }
  f32x4 oacc[4];
  #pragma unroll
  for (int i = 0; i < 4; i++) oacc[i] = (f32x4){0.f,0.f,0.f,0.f};
  float m_i[4] = {-1e30f,-1e30f,-1e30f,-1e30f};
  float l_i[4] = {0.f,0.f,0.f,0.f};
  const short* gsrc = (w==0) ? kh : (w==1) ? kl : (w==2) ? vth : vtl;
  short* myb = (w==0) ? skh : (w==1) ? skl : (w==2) ? svh : svl;
  bool isv = (w >= 2);
  int rloc = lane >> 3, pch = lane & 7;
  for (int kt = ktb; kt < kte; kt++){
    #pragma unroll
    for (int j = 0; j < 8; j++){
      int r = j*8 + rloc;
      int c = pch ^ (r & 7);
      long ga = isv ? (base + (long)r*1024 + kt*64 + c*8)
                    : (base + (long)(kt*64 + r)*64 + c*8);
      gl_lds16(gsrc + ga, myb + j*512);
    }
    __syncthreads();
    f32x4 sfr[4];
    #pragma unroll
    for (int nt = 0; nt < 4; nt++){
      f32x4 c = (f32x4){0.f,0.f,0.f,0.f};
      int krow = (nt*16 + l15) * 64;
      #pragma unroll
      for (int ch = 0; ch < 2; ch++){
        int pc = ((ch*4 + quad) ^ (l15 & 7)) * 8;
        bf16x8 kfh = *(const bf16x8*)&skh[krow + pc];
        bf16x8 kfl = *(const bf16x8*)&skl[krow + pc];
        c = MFMA16(qfh[ch], kfh, c);
        c = MFMA16(qfh[ch], kfl, c);
        c = MFMA16(qfl[ch], kfh, c);
      }
      sfr[nt] = c;
    }
    if (kt == qt){
      #pragma unroll
      for (int nt = 0; nt < 4; nt++)
        #pragma unroll
        for (int rg = 0; rg < 4; rg++){
          int kp = nt*16 + l15, qp = w*16 + quad*4 + rg;
          if (kp > qp) sfr[nt][rg] = -1e30f;
        }
    }
    float rmax[4];
    #pragma unroll
    for (int rg = 0; rg < 4; rg++)
      rmax[rg] = fmaxf(fmaxf(sfr[0][rg], sfr[1][rg]), fmaxf(sfr[2][rg], sfr[3][rg]));
    #pragma unroll
    for (int xm = 1; xm < 16; xm <<= 1)
      #pragma unroll
      for (int rg = 0; rg < 4; rg++)
        rmax[rg] = fmaxf(rmax[rg], __shfl_xor(rmax[rg], xm, 64));
    float alpha[4];
    #pragma unroll
    for (int rg = 0; rg < 4; rg++){
      float mn = fmaxf(m_i[rg], rmax[rg]);
      alpha[rg] = expf(m_i[rg] - mn);
      m_i[rg] = mn;
    }
    float rsum[4] = {0.f,0.f,0.f,0.f};
    #pragma unroll
    for (int nt = 0; nt < 4; nt++)
      #pragma unroll
      for (int rg = 0; rg < 4; rg++){
        float p = expf(sfr[nt][rg] - m_i[rg]);
        sfr[nt][rg] = p; rsum[rg] += p;
      }
    #pragma unroll
    for (int xm = 1; xm < 16; xm <<= 1)
      #pragma unroll
      for (int rg = 0; rg < 4; rg++)
        rsum[rg] += __shfl_xor(rsum[rg], xm, 64);
    #pragma unroll
    for (int rg = 0; rg < 4; rg++) l_i[rg] = l_i[rg]*alpha[rg] + rsum[rg];
    #pragma unroll
    for (int hd = 0; hd < 4; hd++)
      #pragma unroll
      for (int rg = 0; rg < 4; rg++) oacc[hd][rg] *= alpha[rg];
    #pragma unroll
    for (int nt = 0; nt < 4; nt++)
      #pragma unroll
      for (int rg = 0; rg < 4; rg++){
        float p = sfr[nt][rg];
        short hv = f2bf(p);
        sph[w][(quad*4+rg)*72 + nt*16 + l15] = hv;
        spl[w][(quad*4+rg)*72 + nt*16 + l15] = f2bf(p - bf2f(hv));
      }
    bf16x8 pfh[2], pfl[2];
    #pragma unroll
    for (int ch = 0; ch < 2; ch++){
      pfh[ch] = *(const bf16x8*)&sph[w][l15*72 + ch*32 + quad*8];
      pfl[ch] = *(const bf16x8*)&spl[w][l15*72 + ch*32 + quad*8];
    }
    #pragma unroll
    for (int hd = 0; hd < 4; hd++){
      int vrow = (hd*16 + l15) * 64;
      #pragma unroll
      for (int ch = 0; ch < 2; ch++){
        int pc = ((ch*4 + quad) ^ (l15 & 7)) * 8;
        bf16x8 vfh = *(const bf16x8*)&svh[vrow + pc];
        bf16x8 vfl = *(const bf16x8*)&svl[vrow + pc];
        oacc[hd] = MFMA16(pfh[ch], vfh, oacc[hd]);
        oacc[hd] = MFMA16(pfh[ch], vfl, oacc[hd]);
        oacc[hd] = MFMA16(pfl[ch], vfh, oacc[hd]);
      }
    }
    __syncthreads();
  }
  long pb = ((long)(half*24 + bh)*1024);
  #pragma unroll
  for (int hdt = 0; hdt < 4; hdt++)
    #pragma unroll
    for (int rg = 0; rg < 4; rg++){
      int qp = q0 + w*16 + quad*4 + rg;
      po[(pb + qp)*64 + hdt*16 + l15] = oacc[hdt][rg];
    }
  if (l15 == 0){
    #pragma unroll
    for (int rg = 0; rg < 4; rg++){
      int qp = q0 + w*16 + quad*4 + rg;
      pm[pb + qp] = m_i[rg];
      pl[pb + qp] = l_i[rg];
    }
  }
}

// ---------------- attention combine: merge 2 partials -> bf16 hi/lo ---------
__global__ void k_attn_combine(const float* __restrict__ po, const float* __restrict__ pm,
                               const float* __restrict__ pl,
                               short* __restrict__ oh, short* __restrict__ ol){
  int bh = blockIdx.y, tid = threadIdx.x;
  int r = blockIdx.x*64 + (tid >> 2);
  int c0 = (tid & 3) * 16;
  long i0 = (long)bh*1024 + r;
  long i1 = (long)(24 + bh)*1024 + r;
  float m0 = pm[i0], m1 = pm[i1], l0 = pl[i0], l1 = pl[i1];
  float m = fmaxf(m0, m1);
  float a0 = expf(m0 - m), a1 = expf(m1 - m);
  float inv = 1.f / (a0*l0 + a1*l1);
  a0 *= inv; a1 *= inv;
  int b = bh / 12, hh = bh % 12;
  long ob = ((long)(b*1024 + r))*768 + hh*64 + c0;
  short hv[16], lv[16];
  #pragma unroll
  for (int j = 0; j < 4; j++){
    float4 o0 = *(const float4*)&po[i0*64 + c0 + j*4];
    float4 o1 = *(const float4*)&po[i1*64 + c0 + j*4];
    float vs[4] = {a0*o0.x + a1*o1.x, a0*o0.y + a1*o1.y,
                   a0*o0.z + a1*o1.z, a0*o0.w + a1*o1.w};
    #pragma unroll
    for (int q = 0; q < 4; q++){
      short h = f2bf(vs[q]);
      hv[j*4+q] = h; lv[j*4+q] = f2bf(vs[q] - bf2f(h));
    }
  }
  *(bf16x8*)(oh + ob)     = *(bf16x8*)&hv[0];
  *(bf16x8*)(oh + ob + 8) = *(bf16x8*)&hv[8];
  *(bf16x8*)(ol + ob)     = *(bf16x8*)&lv[0];
  *(bf16x8*)(ol + ob + 8) = *(bf16x8*)&lv[8];
}

// ---------------- split GEMM Wo + residual -> h fp32 (gl_lds staging) -------
__global__ __launch_bounds__(256,2) void k_wo(
    const short* __restrict__ Ah, const short* __restrict__ Al,
    const short* __restrict__ Bh, const short* __restrict__ Bl,
    const float* __restrict__ x, const float* __restrict__ bo,
    float* __restrict__ hout){
  int M0 = blockIdx.x * 128, N0 = blockIdx.y * 128;
  __shared__ __align__(16) short lah[128*32], lal[128*32], lbh[128*32], lbl[128*32];
  int tid = threadIdx.x;
  int w = tid >> 6, lane = tid & 63, l15 = lane & 15, quad = lane >> 4;
  int mbase = (w & 1) * 64, nbase = (w >> 1) * 64;
  f32x4 acc[4][4];
  #pragma unroll
  for (int i = 0; i < 4; i++)
    #pragma unroll
    for (int j = 0; j < 4; j++) acc[i][j] = (f32x4){0.f,0.f,0.f,0.f};
  int sr = w*32 + (lane >> 2);
  int sc = ((lane & 3) ^ (sr & 3)) * 8;
  long gA = (long)(M0 + sr)*768 + sc;
  long gB = (long)(N0 + sr)*768 + sc;
  int swq = (quad ^ (l15 & 3)) * 8;
  for (int k0 = 0; k0 < 768; k0 += 32){
    gl_lds16(Ah + gA + k0,          lah + w*1024);
    gl_lds16(Ah + gA + 16*768 + k0, lah + w*1024 + 512);
    gl_lds16(Al + gA + k0,          lal + w*1024);
    gl_lds16(Al + gA + 16*768 + k0, lal + w*1024 + 512);
    gl_lds16(Bh + gB + k0,          lbh + w*1024);
    gl_lds16(Bh + gB + 16*768 + k0, lbh + w*1024 + 512);
    gl_lds16(Bl + gB + k0,          lbl + w*1024);
    gl_lds16(Bl + gB + 16*768 + k0, lbl + w*1024 + 512);
    __syncthreads();
    bf16x8 afh[4], afl[4];
    #pragma unroll
    for (int mt = 0; mt < 4; mt++){
      afh[mt] = *(const bf16x8*)&lah[(mbase+mt*16+l15)*32 + swq];
      afl[mt] = *(const bf16x8*)&lal[(mbase+mt*16+l15)*32 + swq];
    }
    #pragma unroll
    for (int nt = 0; nt < 4; nt++){
      bf16x8 bfh = *(const bf16x8*)&lbh[(nbase+nt*16+l15)*32 + swq];
      bf16x8 bfl = *(const bf16x8*)&lbl[(nbase+nt*16+l15)*32 + swq];
      #pragma unroll
      for (int mt = 0; mt < 4; mt++){
        acc[mt][nt] = MFMA16(afh[mt], bfh, acc[mt][nt]);
        acc[mt][nt] = MFMA16(afh[mt], bfl, acc[mt][nt]);
        acc[mt][nt] = MFMA16(afl[mt], bfh, acc[mt][nt]);
      }
    }
    __syncthreads();
  }
  #pragma unroll
  for (int mt = 0; mt < 4; mt++)
    #pragma unroll
    for (int nt = 0; nt < 4; nt++)
      #pragma unroll
      for (int rg = 0; rg < 4; rg++){
        int m = M0 + mbase + mt*16 + quad*4 + rg;
        int n = N0 + nbase + nt*16 + l15;
        hout[(long)m*768 + n] = acc[mt][nt][rg] + x[(long)m*768 + n] + bo[n];
      }
}

// ---------------- LN2 + router ----------------
__global__ void k_zero(int* cnt){ if (threadIdx.x < 8) cnt[threadIdx.x] = 0; }

__global__ void k_router(const float* __restrict__ h, const float* __restrict__ g,
                         const float* __restrict__ bb, const float* __restrict__ Wr,
                         const float* __restrict__ br, short* __restrict__ xn2,
                         int* __restrict__ cnt, int* __restrict__ perm,
                         float* __restrict__ gw){
  int t = blockIdx.x, tid = threadIdx.x;
  const float* xr = h + (long)t * 768;
  float v[3];
  #pragma unroll
  for (int j = 0; j < 3; j++) v[j] = xr[tid + 256*j];
  float s = v[0]+v[1]+v[2];
  float q = v[0]*v[0]+v[1]*v[1]+v[2]*v[2];
  #pragma unroll
  for (int o = 32; o > 0; o >>= 1){ s += __shfl_down(s,o,64); q += __shfl_down(q,o,64); }
  __shared__ float ss[4], qs[4];
  __shared__ float lred[4][8];
  int w = tid >> 6;
  if ((tid & 63) == 0){ ss[w] = s; qs[w] = q; }
  __syncthreads();
  float St = ss[0]+ss[1]+ss[2]+ss[3], Qt = qs[0]+qs[1]+qs[2]+qs[3];
  float mean = St * (1.f/768.f);
  float var  = Qt * (1.f/768.f) - mean*mean;
  float inv  = 1.f / sqrtf(var + 1e-5f);
  float part[8] = {0,0,0,0,0,0,0,0};
  #pragma unroll
  for (int j = 0; j < 3; j++){
    int d = tid + 256*j;
    float xn = (v[j]-mean)*inv*g[d] + bb[d];
    xn2[(long)t*768 + d] = f2bf(xn);
    #pragma unroll
    for (int e = 0; e < 8; e++) part[e] += xn * Wr[d*8 + e];
  }
  #pragma unroll
  for (int o = 32; o > 0; o >>= 1)
    #pragma unroll
    for (int e = 0; e < 8; e++) part[e] += __shfl_down(part[e], o, 64);
  if ((tid & 63) == 0)
    #pragma unroll
    for (int e = 0; e < 8; e++) lred[w][e] = part[e];
  __syncthreads();
  if (tid == 0){
    float lg[8];
    #pragma unroll
    for (int e = 0; e < 8; e++) lg[e] = lred[0][e]+lred[1][e]+lred[2][e]+lred[3][e] + br[e];
    int i1 = 0;
    for (int e = 1; e < 8; e++) if (lg[e] > lg[i1]) i1 = e;
    int i2 = -1;
    for (int e = 0; e < 8; e++){ if (e == i1) continue; if (i2 < 0 || lg[e] > lg[i2]) i2 = e; }
    float e2 = expf(lg[i2] - lg[i1]);
    float is = 1.f / (1.f + e2);
    gw[t*2]   = is;
    gw[t*2+1] = e2 * is;
    int p1 = atomicAdd(&cnt[i1], 1); perm[i1*2048 + p1] = t*2;
    int p2 = atomicAdd(&cnt[i2], 1); perm[i2*2048 + p2] = t*2 + 1;
  }
}

// scan with 128-padding: per-expert padded offsets, per-Mblock expert id
__global__ void k_scan(const int* __restrict__ cnt, int* __restrict__ poffs,
                       int* __restrict__ eidx, int* __restrict__ ptot){
  if (threadIdx.x == 0){
    int p = 0;
    for (int e = 0; e < 8; e++){
      poffs[e] = p;
      int pc = (cnt[e] + 127) & ~127;
      for (int j = p >> 7; j < (p + pc) >> 7; j++) eidx[j] = e;
      p += pc;
    }
    *ptot = p;
    for (int j = p >> 7; j < 40; j++) eidx[j] = 7;
  }
}

// build flat padded slot list (perm value or -1)
__global__ void k_fill(const int* __restrict__ cnt, const int* __restrict__ poffs,
                       const int* __restrict__ eidx, const int* __restrict__ perm,
                       const int* __restrict__ ptot, int* __restrict__ pperm){
  int i = blockIdx.x*256 + threadIdx.x;   // 5120
  int e = eidx[i >> 7];
  int li = i - poffs[e];
  int v = -1;
  if (i < *ptot && li >= 0 && li < cnt[e]) v = perm[e*2048 + li];
  pperm[i] = v;
}

// ---------------- MoE GEMM1: h1[p] = gelu(xn2[tok(p)] @ W1T[e] + b1) --------
// grid (40 Mblk, 24 Nblk). BK=64. padded slots, no early-exit imbalance.
__global__ __launch_bounds__(256,3) void k_moe1(
    const short* __restrict__ xn2, const short* __restrict__ W1T,
    const float* __restrict__ b1,
    const int* __restrict__ eidx, const int* __restrict__ pperm,
    const int* __restrict__ ptot, short* __restrict__ h1){
  int Mb = blockIdx.x;
  int M0 = Mb * 128;
  if (M0 >= *ptot) return;
  int e = eidx[Mb];
  int N0 = blockIdx.y * 128;
  const short* Bp = W1T + (long)e * 3072 * 768;
  __shared__ __align__(16) short la[128*64], lb[128*64];
  __shared__ int rtok[128];
  int tid = threadIdx.x, w = tid >> 6, lane = tid & 63, l15 = lane & 15, quad = lane >> 4;
  if (tid < 128) rtok[tid] = pperm[M0 + tid];
  __syncthreads();
  int rl = lane >> 3, pch = lane & 7;
  long gA[4], gB[4];
  #pragma unroll
  for (int j = 0; j < 4; j++){
    int r = w*32 + j*8 + rl;
    int c = pch ^ (r & 7);
    int tk = rtok[r]; tk = (tk >= 0) ? (tk >> 1) : 0;
    gA[j] = (long)tk*768 + c*8;
    gB[j] = (long)(N0 + r)*768 + c*8;
  }
  short* ldA = la + w*2048;
  short* ldB = lb + w*2048;
  f32x4 acc[4][4];
  #pragma unroll
  for (int i = 0; i < 4; i++)
    #pragma unroll
    for (int j = 0; j < 4; j++) acc[i][j] = (f32x4){0.f,0.f,0.f,0.f};
  int mbase = (w & 1) * 64, nbase = (w >> 1) * 64;
  for (int k0 = 0; k0 < 768; k0 += 64){
    #pragma unroll
    for (int j = 0; j < 4; j++) gl_lds16(xn2 + gA[j] + k0, ldA + j*512);
    #pragma unroll
    for (int j = 0; j < 4; j++) gl_lds16(Bp  + gB[j] + k0, ldB + j*512);
    __syncthreads();
    #pragma unroll
    for (int kk = 0; kk < 2; kk++){
      int swq = ((kk*4 + quad) ^ (l15 & 7)) * 8;
      bf16x8 af[4];
      #pragma unroll
      for (int mt = 0; mt < 4; mt++)
        af[mt] = *(const bf16x8*)&la[(mbase+mt*16+l15)*64 + swq];
      #pragma unroll
      for (int nt = 0; nt < 4; nt++){
        bf16x8 bf = *(const bf16x8*)&lb[(nbase+nt*16+l15)*64 + swq];
        #pragma unroll
        for (int mt = 0; mt < 4; mt++) acc[mt][nt] = MFMA16(af[mt], bf, acc[mt][nt]);
      }
    }
    __syncthreads();
  }
  #pragma unroll
  for (int mt = 0; mt < 4; mt++)
    #pragma unroll
    for (int nt = 0; nt < 4; nt++)
      #pragma unroll
      for (int rg = 0; rg < 4; rg++){
        int ml = mbase + mt*16 + quad*4 + rg;
        if (rtok[ml] >= 0){
          int n = N0 + nbase + nt*16 + l15;
          float vv = acc[mt][nt][rg] + b1[e*3072 + n];
          float gl = 0.5f * vv * (1.f + erff(vv * 0.70710678118654752f));
          h1[(long)(M0 + ml)*3072 + n] = f2bf(gl);
        }
      }
}

// ---------------- MoE GEMM2: eo[tok] += gw*(h1 @ W2T[e] + b2), split-K=4 ----
// grid (40 Mblk, 6 Nblk, 4 ks). BK=64, K/split = 768.
__global__ __launch_bounds__(256,3) void k_moe2(
    const short* __restrict__ h1, const short* __restrict__ W2T,
    const float* __restrict__ b2,
    const int* __restrict__ eidx, const int* __restrict__ pperm,
    const int* __restrict__ ptot, const float* __restrict__ gw,
    float* __restrict__ eo){
  int Mb = blockIdx.x;
  int M0 = Mb * 128;
  if (M0 >= *ptot) return;
  int e = eidx[Mb];
  int N0 = blockIdx.y * 128;
  int ks = blockIdx.z;
  const short* Bp = W2T + (long)e * 768 * 3072;
  __shared__ __align__(16) short la[128*64], lb[128*64];
  __shared__ int rtok[128];
  int tid = threadIdx.x, w = tid >> 6, lane = tid & 63, l15 = lane & 15, quad = lane >> 4;
  if (tid < 128) rtok[tid] = pperm[M0 + tid];
  __syncthreads();
  int rl = lane >> 3, pch = lane & 7;
  int kbeg = ks * 768;
  long gA[4], gB[4];
  #pragma unroll
  for (int j = 0; j < 4; j++){
    int r = w*32 + j*8 + rl;
    int c = pch ^ (r & 7);
    gA[j] = (long)(M0 + r)*3072 + kbeg + c*8;
    gB[j] = (long)(N0 + r)*3072 + kbeg + c*8;
  }
  short* ldA = la + w*2048;
  short* ldB = lb + w*2048;
  f32x4 acc[4][4];
  #pragma unroll
  for (int i = 0; i < 4; i++)
    #pragma unroll
    for (int j = 0; j < 4; j++) acc[i][j] = (f32x4){0.f,0.f,0.f,0.f};
  int mbase = (w & 1) * 64, nbase = (w >> 1) * 64;
  for (int k0 = 0; k0 < 768; k0 += 64){
    #pragma unroll
    for (int j = 0; j < 4; j++) gl_lds16(h1 + gA[j] + k0, ldA + j*512);
    #pragma unroll
    for (int j = 0; j < 4; j++) gl_lds16(Bp + gB[j] + k0, ldB + j*512);
    __syncthreads();
    #pragma unroll
    for (int kk = 0; kk < 2; kk++){
      int swq = ((kk*4 + quad) ^ (l15 & 7)) * 8;
      bf16x8 af[4];
      #pragma unroll
      for (int mt = 0; mt < 4; mt++)
        af[mt] = *(const bf16x8*)&la[(mbase+mt*16+l15)*64 + swq];
      #pragma unroll
      for (int nt = 0; nt < 4; nt++){
        bf16x8 bf = *(const bf16x8*)&lb[(nbase+nt*16+l15)*64 + swq];
        #pragma unroll
        for (int mt = 0; mt < 4; mt++) acc[mt][nt] = MFMA16(af[mt], bf, acc[mt][nt]);
      }
    }
    __syncthreads();
  }
  #pragma unroll
  for (int mt = 0; mt < 4; mt++)
    #pragma unroll
    for (int nt = 0; nt < 4; nt++)
      #pragma unroll
      for (int rg = 0; rg < 4; rg++){
        int ml = mbase + mt*16 + quad*4 + rg;
        int dv = rtok[ml];
        if (dv >= 0){
          int n = N0 + nbase + nt*16 + l15;
          float vv = acc[mt][nt][rg] + (ks ? 0.f : b2[e*768 + n]);
          atomicAdd(&eo[(long)dv*768 + n], vv * gw[dv]);
        }
      }
}

// ---------------- final combine: out = h + eo0 + eo1 ----------------
__global__ void k_combine(const float* __restrict__ h, const float* __restrict__ eo,
                          float* __restrict__ out){
  int i = blockIdx.x * 256 + threadIdx.x;     // 393216 float4s
  int t = i / 192, c = i - t * 192;
  const float4* h4 = (const float4*)h;
  const float4* e4 = (const float4*)eo;
  float4 a  = h4[i];
  float4 x0 = e4[(long)(2*t)*192 + c];
  float4 x1 = e4[(long)(2*t+1)*192 + c];
  float4 o;
  o.x = a.x + x0.x + x1.x;
  o.y = a.y + x0.y + x1.y;
  o.z = a.z + x0.z + x1.z;
  o.w = a.w + x0.w + x1.w;
  ((float4*)out)[i] = o;
}

// ---------------- launcher ----------------
extern "C" void kernel_launch(void* const* d_in, const int* in_sizes, int n_in,
                              void* d_out, int out_size, void* d_ws, size_t ws_size,
                              hipStream_t stream){
  const float* x    = (const float*)d_in[0];
  const float* ln1g = (const float*)d_in[1];
  const float* ln1b = (const float*)d_in[2];
  const float* Wq   = (const float*)d_in[3];
  const float* Wk   = (const float*)d_in[4];
  const float* Wv   = (const float*)d_in[5];
  const float* Wo   = (const float*)d_in[6];
  const float* bo   = (const float*)d_in[7];
  const float* ln2g = (const float*)d_in[8];
  const float* ln2b = (const float*)d_in[9];
  const float* Wr   = (const float*)d_in[10];
  const float* br   = (const float*)d_in[11];
  const float* W1   = (const float*)d_in[12];
  const float* b1   = (const float*)d_in[13];
  const float* W2   = (const float*)d_in[14];
  const float* b2   = (const float*)d_in[15];

  char* ws = (char*)d_ws;
  size_t off = 0;
  auto alloc = [&](size_t bytes) -> void* {
    void* p = ws + off;
    off += (bytes + 255) & ~(size_t)255;
    return p;
  };
  short* WQKVH = (short*)alloc(2304l*768*2);
  short* WQKVL = (short*)alloc(2304l*768*2);
  short* WOH   = (short*)alloc(768l*768*2);
  short* WOL   = (short*)alloc(768l*768*2);
  short* W1T   = (short*)alloc(8l*3072*768*2);
  short* W2T   = (short*)alloc(8l*768*3072*2);
  short* XN1H  = (short*)alloc(2048l*768*2);
  short* XN1L  = (short*)alloc(2048l*768*2);
  short* QH    = (short*)alloc(2048l*768*2);
  short* QL    = (short*)alloc(2048l*768*2);
  short* KH    = (short*)alloc(2048l*768*2);
  short* KL    = (short*)alloc(2048l*768*2);
  short* VTH   = (short*)alloc(2048l*768*2);
  short* VTL   = (short*)alloc(2048l*768*2);
  short* ATH   = (short*)alloc(2048l*768*2);
  short* ATL   = (short*)alloc(2048l*768*2);
  float* HBUF  = (float*)alloc(2048l*768*4);
  short* XN2   = (short*)alloc(2048l*768*2);
  short* H1    = (short*)alloc(5120l*3072*2);
  float* EO    = (float*)alloc(4096l*768*4);
  float* PO    = (float*)alloc(2l*24*1024*64*4);
  float* PM    = (float*)alloc(2l*24*1024*4);
  float* PL    = (float*)alloc(2l*24*1024*4);
  int*   CNT   = (int*)alloc(8*4);
  int*   POFF  = (int*)alloc(8*4);
  int*   EIDX  = (int*)alloc(40*4);
  int*   PTOT  = (int*)alloc(4);
  int*   PERM  = (int*)alloc(8l*2048*4);
  int*   PPERM = (int*)alloc(5120*4);
  float* GW    = (float*)alloc(4096*4);
  (void)ws_size; (void)in_sizes; (void)n_in; (void)out_size;

  // weight prep (transpose + bf16 hi/lo split)
  k_transpose<<<dim3(24,24,1),256,0,stream>>>(Wq, 0, WQKVH,             WQKVL,             0, 768, 768);
  k_transpose<<<dim3(24,24,1),256,0,stream>>>(Wk, 0, WQKVH + 768l*768,  WQKVL + 768l*768,  0, 768, 768);
  k_transpose<<<dim3(24,24,1),256,0,stream>>>(Wv, 0, WQKVH + 1536l*768, WQKVL + 1536l*768, 0, 768, 768);
  k_transpose<<<dim3(24,24,1),256,0,stream>>>(Wo, 0, WOH, WOL, 0, 768, 768);
  k_transpose<<<dim3(96,24,8),256,0,stream>>>(W1, 768l*3072, W1T, nullptr, 3072l*768, 768, 3072);
  k_transpose<<<dim3(24,96,8),256,0,stream>>>(W2, 3072l*768, W2T, nullptr, 768l*3072, 3072, 768);

  // attention path (split-bf16 precision)
  k_ln1<<<2048,256,0,stream>>>(x, ln1g, ln1b, XN1H, XN1L);
  k_qkv<<<dim3(16,18),256,0,stream>>>(XN1H, XN1L, WQKVH, WQKVL, QH, QL, KH, KL, VTH, VTL);
  k_attn<<<dim3(32,24),256,0,stream>>>(QH, QL, KH, KL, VTH, VTL, PO, PM, PL);
  k_attn_combine<<<dim3(16,24),256,0,stream>>>(PO, PM, PL, ATH, ATL);
  k_wo<<<dim3(16,6),256,0,stream>>>(ATH, ATL, WOH, WOL, x, bo, HBUF);

  // router + MoE
  k_zero<<<1,64,0,stream>>>(CNT);
  k_router<<<2048,256,0,stream>>>(HBUF, ln2g, ln2b, Wr, br, XN2, CNT, PERM, GW);
  k_scan<<<1,64,0,stream>>>(CNT, POFF, EIDX, PTOT);
  k_fill<<<20,256,0,stream>>>(CNT, POFF, EIDX, PERM, PTOT, PPERM);
  hipMemsetAsync(EO, 0, 4096l*768*4, stream);
  k_moe1<<<dim3(40,24),256,0,stream>>>(XN2, W1T, b1, EIDX, PPERM, PTOT, H1);
  k_moe2<<<dim3(40,6,4),256,0,stream>>>(H1, W2T, b2, EIDX, PPERM, PTOT, GW, EO);
  k_combine<<<1536,256,0,stream>>>(HBUF, EO, (float*)d_out);
}

// Round 5
// 511.784 us; speedup vs baseline: 1.1143x; 1.1143x over previous
//
#include <hip/hip_runtime.h>

// ---------------- common helpers ----------------
using bf16x8 = __attribute__((ext_vector_type(8))) short;
using f32x4  = __attribute__((ext_vector_type(4))) float;

#define DEV __device__ __forceinline__

DEV short f2bf(float x){
  unsigned u = __float_as_uint(x);
  u += 0x7fffu + ((u >> 16) & 1u);
  return (short)(u >> 16);
}
DEV float bf2f(short h){ return __uint_as_float(((unsigned)(unsigned short)h) << 16); }

#define MFMA16(a,b,c) __builtin_amdgcn_mfma_f32_16x16x32_bf16(a,b,c,0,0,0)

// async global->LDS, 16B per lane; LDS dest is wave-uniform base + lane*16
DEV void gl_lds16(const void* g, void* l){
  __builtin_amdgcn_global_load_lds(
      (const __attribute__((address_space(1))) unsigned*)g,
      (__attribute__((address_space(3))) unsigned*)l, 16, 0, 0);
}

// Problem constants: B=2 S=1024 D=768 H=12 HD=64 E=8 DF=3072 K=2, T=2048

// ---------------- transpose + fp32->bf16(hi/lo) convert ----------------
__global__ void k_transpose(const float* __restrict__ src, long sbatch,
                            short* __restrict__ dhi, short* __restrict__ dlo, long dbatch,
                            int R, int C){
  __shared__ float tile[32][33];
  const float* s = src + (long)blockIdx.z * sbatch;
  int c0 = blockIdx.x * 32, r0 = blockIdx.y * 32;
  int tx = threadIdx.x & 31, ty = threadIdx.x >> 5;   // 32x8
  #pragma unroll
  for (int i = 0; i < 4; i++)
    tile[ty + 8*i][tx] = s[(long)(r0 + ty + 8*i) * C + c0 + tx];
  __syncthreads();
  #pragma unroll
  for (int i = 0; i < 4; i++){
    int c = c0 + ty + 8*i;
    float v = tile[tx][ty + 8*i];
    short hv = f2bf(v);
    long o = (long)blockIdx.z * dbatch + (long)c * R + r0 + tx;
    dhi[o] = hv;
    if (dlo) dlo[o] = f2bf(v - bf2f(hv));
  }
}

// ---------------- LayerNorm1: x -> xn1 hi/lo bf16 ----------------
__global__ void k_ln1(const float* __restrict__ x, const float* __restrict__ g,
                      const float* __restrict__ bb,
                      short* __restrict__ xh, short* __restrict__ xl){
  int t = blockIdx.x, tid = threadIdx.x;
  const float* xr = x + (long)t * 768;
  float v[3];
  #pragma unroll
  for (int j = 0; j < 3; j++) v[j] = xr[tid + 256*j];
  float s = v[0]+v[1]+v[2];
  float q = v[0]*v[0]+v[1]*v[1]+v[2]*v[2];
  #pragma unroll
  for (int o = 32; o > 0; o >>= 1){ s += __shfl_down(s,o,64); q += __shfl_down(q,o,64); }
  __shared__ float ss[4], qs[4];
  int w = tid >> 6;
  if ((tid & 63) == 0){ ss[w] = s; qs[w] = q; }
  __syncthreads();
  float St = ss[0]+ss[1]+ss[2]+ss[3], Qt = qs[0]+qs[1]+qs[2]+qs[3];
  float mean = St * (1.f/768.f);
  float var  = Qt * (1.f/768.f) - mean*mean;
  float inv  = 1.f / sqrtf(var + 1e-5f);
  #pragma unroll
  for (int j = 0; j < 3; j++){
    int d = tid + 256*j;
    float xn = (v[j]-mean)*inv*g[d] + bb[d];
    short hv = f2bf(xn);
    xh[(long)t*768 + d] = hv;
    xl[(long)t*768 + d] = f2bf(xn - bf2f(hv));
  }
}

// ---------------- split-bf16 GEMM: qkv = xn1 @ Wqkv (gl_lds staging) --------
__global__ __launch_bounds__(256,2) void k_qkv(
    const short* __restrict__ Ah, const short* __restrict__ Al,
    const short* __restrict__ Bh, const short* __restrict__ Bl,
    short* __restrict__ qh, short* __restrict__ ql,
    short* __restrict__ kh, short* __restrict__ kl,
    short* __restrict__ vh, short* __restrict__ vl){
  int M0 = blockIdx.x * 128, N0 = blockIdx.y * 128;
  __shared__ __align__(16) short lah[128*32], lal[128*32], lbh[128*32], lbl[128*32];
  int tid = threadIdx.x;
  int w = tid >> 6, lane = tid & 63, l15 = lane & 15, quad = lane >> 4;
  int mbase = (w & 1) * 64, nbase = (w >> 1) * 64;
  f32x4 acc[4][4];
  #pragma unroll
  for (int i = 0; i < 4; i++)
    #pragma unroll
    for (int j = 0; j < 4; j++) acc[i][j] = (f32x4){0.f,0.f,0.f,0.f};
  int sr = w*32 + (lane >> 2);
  int sc = ((lane & 3) ^ (sr & 3)) * 8;
  long gA = (long)(M0 + sr)*768 + sc;
  long gB = (long)(N0 + sr)*768 + sc;
  int swq = (quad ^ (l15 & 3)) * 8;
  for (int k0 = 0; k0 < 768; k0 += 32){
    gl_lds16(Ah + gA + k0,          lah + w*1024);
    gl_lds16(Ah + gA + 16*768 + k0, lah + w*1024 + 512);
    gl_lds16(Al + gA + k0,          lal + w*1024);
    gl_lds16(Al + gA + 16*768 + k0, lal + w*1024 + 512);
    gl_lds16(Bh + gB + k0,          lbh + w*1024);
    gl_lds16(Bh + gB + 16*768 + k0, lbh + w*1024 + 512);
    gl_lds16(Bl + gB + k0,          lbl + w*1024);
    gl_lds16(Bl + gB + 16*768 + k0, lbl + w*1024 + 512);
    __syncthreads();
    bf16x8 afh[4], afl[4];
    #pragma unroll
    for (int mt = 0; mt < 4; mt++){
      afh[mt] = *(const bf16x8*)&lah[(mbase+mt*16+l15)*32 + swq];
      afl[mt] = *(const bf16x8*)&lal[(mbase+mt*16+l15)*32 + swq];
    }
    #pragma unroll
    for (int nt = 0; nt < 4; nt++){
      bf16x8 bfh = *(const bf16x8*)&lbh[(nbase+nt*16+l15)*32 + swq];
      bf16x8 bfl = *(const bf16x8*)&lbl[(nbase+nt*16+l15)*32 + swq];
      #pragma unroll
      for (int mt = 0; mt < 4; mt++){
        acc[mt][nt] = MFMA16(afh[mt], bfh, acc[mt][nt]);
        acc[mt][nt] = MFMA16(afh[mt], bfl, acc[mt][nt]);
        acc[mt][nt] = MFMA16(afl[mt], bfh, acc[mt][nt]);
      }
    }
    __syncthreads();
  }
  // epilogue: scatter into q[bh][s][hd], k[bh][s][hd], vT[bh][hd][s]
  #pragma unroll
  for (int mt = 0; mt < 4; mt++){
    #pragma unroll
    for (int nt = 0; nt < 4; nt++){
      #pragma unroll
      for (int rg = 0; rg < 4; rg++){
        int m = M0 + mbase + mt*16 + quad*4 + rg;
        int n = N0 + nbase + nt*16 + l15;
        float vv = acc[mt][nt][rg];
        int bi = m >> 10, si = m & 1023;
        if (n < 768){
          float sv = vv * 0.125f;              // fold 1/sqrt(HD)
          short hv = f2bf(sv);
          int hh = n >> 6, hd = n & 63;
          long o = (((long)(bi*12+hh)*1024) + si)*64 + hd;
          qh[o] = hv; ql[o] = f2bf(sv - bf2f(hv));
        } else if (n < 1536){
          int n2 = n - 768;
          short hv = f2bf(vv);
          int hh = n2 >> 6, hd = n2 & 63;
          long o = (((long)(bi*12+hh)*1024) + si)*64 + hd;
          kh[o] = hv; kl[o] = f2bf(vv - bf2f(hv));
        } else {
          int n2 = n - 1536;
          short hv = f2bf(vv);
          int hh = n2 >> 6, hd = n2 & 63;
          long o = (((long)(bi*12+hh)*64) + hd)*1024 + si;
          vh[o] = hv; vl[o] = f2bf(vv - bf2f(hv));
        }
      }
    }
  }
}

// ---------------- flash attention, split-bf16, causal, split-K=2 ------------
__global__ __launch_bounds__(256,3) void k_attn(
    const short* __restrict__ qh, const short* __restrict__ ql,
    const short* __restrict__ kh, const short* __restrict__ kl,
    const short* __restrict__ vth, const short* __restrict__ vtl,
    float* __restrict__ po, float* __restrict__ pm, float* __restrict__ pl){
  int qt = blockIdx.x >> 1, half = blockIdx.x & 1, bh = blockIdx.y;
  int q0 = qt * 64;
  long base = (long)bh * 1024 * 64;
  int ktb = half ? ((qt + 2) >> 1) : 0;
  int kte = half ? (qt + 1) : ((qt + 2) >> 1);
  __shared__ __align__(16) short skh[64*64], skl[64*64], svh[64*64], svl[64*64];
  __shared__ __align__(16) short sph[4][16*72], spl[4][16*72];
  int tid = threadIdx.x, w = tid >> 6, lane = tid & 63, l15 = lane & 15, quad = lane >> 4;
  bf16x8 qfh[2], qfl[2];
  #pragma unroll
  for (int c = 0; c < 2; c++){
    long qa = base + (long)(q0 + w*16 + l15)*64 + c*32 + quad*8;
    qfh[c] = *(const bf16x8*)(qh + qa);
    qfl[c] = *(const bf16x8*)(ql + qa);
  }
  f32x4 oacc[4];
  #pragma unroll
  for (int i = 0; i < 4; i++) oacc[i] = (f32x4){0.f,0.f,0.f,0.f};
  float m_i[4] = {-1e30f,-1e30f,-1e30f,-1e30f};
  float l_i[4] = {0.f,0.f,0.f,0.f};
  const short* gsrc = (w==0) ? kh : (w==1) ? kl : (w==2) ? vth : vtl;
  short* myb = (w==0) ? skh : (w==1) ? skl : (w==2) ? svh : svl;
  bool isv = (w >= 2);
  int rloc = lane >> 3, pch = lane & 7;
  for (int kt = ktb; kt < kte; kt++){
    #pragma unroll
    for (int j = 0; j < 8; j++){
      int r = j*8 + rloc;
      int c = pch ^ (r & 7);
      long ga = isv ? (base + (long)r*1024 + kt*64 + c*8)
                    : (base + (long)(kt*64 + r)*64 + c*8);
      gl_lds16(gsrc + ga, myb + j*512);
    }
    __syncthreads();
    f32x4 sfr[4];
    #pragma unroll
    for (int nt = 0; nt < 4; nt++){
      f32x4 c = (f32x4){0.f,0.f,0.f,0.f};
      int krow = (nt*16 + l15) * 64;
      #pragma unroll
      for (int ch = 0; ch < 2; ch++){
        int pc = ((ch*4 + quad) ^ (l15 & 7)) * 8;
        bf16x8 kfh = *(const bf16x8*)&skh[krow + pc];
        bf16x8 kfl = *(const bf16x8*)&skl[krow + pc];
        c = MFMA16(qfh[ch], kfh, c);
        c = MFMA16(qfh[ch], kfl, c);
        c = MFMA16(qfl[ch], kfh, c);
      }
      sfr[nt] = c;
    }
    if (kt == qt){
      #pragma unroll
      for (int nt = 0; nt < 4; nt++)
        #pragma unroll
        for (int rg = 0; rg < 4; rg++){
          int kp = nt*16 + l15, qp = w*16 + quad*4 + rg;
          if (kp > qp) sfr[nt][rg] = -1e30f;
        }
    }
    float rmax[4];
    #pragma unroll
    for (int rg = 0; rg < 4; rg++)
      rmax[rg] = fmaxf(fmaxf(sfr[0][rg], sfr[1][rg]), fmaxf(sfr[2][rg], sfr[3][rg]));
    #pragma unroll
    for (int xm = 1; xm < 16; xm <<= 1)
      #pragma unroll
      for (int rg = 0; rg < 4; rg++)
        rmax[rg] = fmaxf(rmax[rg], __shfl_xor(rmax[rg], xm, 64));
    float alpha[4];
    #pragma unroll
    for (int rg = 0; rg < 4; rg++){
      float mn = fmaxf(m_i[rg], rmax[rg]);
      alpha[rg] = expf(m_i[rg] - mn);
      m_i[rg] = mn;
    }
    float rsum[4] = {0.f,0.f,0.f,0.f};
    #pragma unroll
    for (int nt = 0; nt < 4; nt++)
      #pragma unroll
      for (int rg = 0; rg < 4; rg++){
        float p = expf(sfr[nt][rg] - m_i[rg]);
        sfr[nt][rg] = p; rsum[rg] += p;
      }
    #pragma unroll
    for (int xm = 1; xm < 16; xm <<= 1)
      #pragma unroll
      for (int rg = 0; rg < 4; rg++)
        rsum[rg] += __shfl_xor(rsum[rg], xm, 64);
    #pragma unroll
    for (int rg = 0; rg < 4; rg++) l_i[rg] = l_i[rg]*alpha[rg] + rsum[rg];
    #pragma unroll
    for (int hd = 0; hd < 4; hd++)
      #pragma unroll
      for (int rg = 0; rg < 4; rg++) oacc[hd][rg] *= alpha[rg];
    #pragma unroll
    for (int nt = 0; nt < 4; nt++)
      #pragma unroll
      for (int rg = 0; rg < 4; rg++){
        float p = sfr[nt][rg];
        short hv = f2bf(p);
        sph[w][(quad*4+rg)*72 + nt*16 + l15] = hv;
        spl[w][(quad*4+rg)*72 + nt*16 + l15] = f2bf(p - bf2f(hv));
      }
    bf16x8 pfh[2], pfl[2];
    #pragma unroll
    for (int ch = 0; ch < 2; ch++){
      pfh[ch] = *(const bf16x8*)&sph[w][l15*72 + ch*32 + quad*8];
      pfl[ch] = *(const bf16x8*)&spl[w][l15*72 + ch*32 + quad*8];
    }
    #pragma unroll
    for (int hd = 0; hd < 4; hd++){
      int vrow = (hd*16 + l15) * 64;
      #pragma unroll
      for (int ch = 0; ch < 2; ch++){
        int pc = ((ch*4 + quad) ^ (l15 & 7)) * 8;
        bf16x8 vfh = *(const bf16x8*)&svh[vrow + pc];
        bf16x8 vfl = *(const bf16x8*)&svl[vrow + pc];
        oacc[hd] = MFMA16(pfh[ch], vfh, oacc[hd]);
        oacc[hd] = MFMA16(pfh[ch], vfl, oacc[hd]);
        oacc[hd] = MFMA16(pfl[ch], vfh, oacc[hd]);
      }
    }
    __syncthreads();
  }
  long pb = ((long)(half*24 + bh)*1024);
  #pragma unroll
  for (int hdt = 0; hdt < 4; hdt++)
    #pragma unroll
    for (int rg = 0; rg < 4; rg++){
      int qp = q0 + w*16 + quad*4 + rg;
      po[(pb + qp)*64 + hdt*16 + l15] = oacc[hdt][rg];
    }
  if (l15 == 0){
    #pragma unroll
    for (int rg = 0; rg < 4; rg++){
      int qp = q0 + w*16 + quad*4 + rg;
      pm[pb + qp] = m_i[rg];
      pl[pb + qp] = l_i[rg];
    }
  }
}

// ---------------- attention combine: merge 2 partials -> bf16 hi/lo ---------
__global__ void k_attn_combine(const float* __restrict__ po, const float* __restrict__ pm,
                               const float* __restrict__ pl,
                               short* __restrict__ oh, short* __restrict__ ol){
  int bh = blockIdx.y, tid = threadIdx.x;
  int r = blockIdx.x*64 + (tid >> 2);
  int c0 = (tid & 3) * 16;
  long i0 = (long)bh*1024 + r;
  long i1 = (long)(24 + bh)*1024 + r;
  float m0 = pm[i0], m1 = pm[i1], l0 = pl[i0], l1 = pl[i1];
  float m = fmaxf(m0, m1);
  float a0 = expf(m0 - m), a1 = expf(m1 - m);
  float inv = 1.f / (a0*l0 + a1*l1);
  a0 *= inv; a1 *= inv;
  int b = bh / 12, hh = bh % 12;
  long ob = ((long)(b*1024 + r))*768 + hh*64 + c0;
  short hv[16], lv[16];
  #pragma unroll
  for (int j = 0; j < 4; j++){
    float4 o0 = *(const float4*)&po[i0*64 + c0 + j*4];
    float4 o1 = *(const float4*)&po[i1*64 + c0 + j*4];
    float vs[4] = {a0*o0.x + a1*o1.x, a0*o0.y + a1*o1.y,
                   a0*o0.z + a1*o1.z, a0*o0.w + a1*o1.w};
    #pragma unroll
    for (int q = 0; q < 4; q++){
      short h = f2bf(vs[q]);
      hv[j*4+q] = h; lv[j*4+q] = f2bf(vs[q] - bf2f(h));
    }
  }
  *(bf16x8*)(oh + ob)     = *(bf16x8*)&hv[0];
  *(bf16x8*)(oh + ob + 8) = *(bf16x8*)&hv[8];
  *(bf16x8*)(ol + ob)     = *(bf16x8*)&lv[0];
  *(bf16x8*)(ol + ob + 8) = *(bf16x8*)&lv[8];
}

// ---------------- split GEMM Wo + residual -> h fp32 (gl_lds staging) -------
__global__ __launch_bounds__(256,2) void k_wo(
    const short* __restrict__ Ah, const short* __restrict__ Al,
    const short* __restrict__ Bh, const short* __restrict__ Bl,
    const float* __restrict__ x, const float* __restrict__ bo,
    float* __restrict__ hout){
  int M0 = blockIdx.x * 128, N0 = blockIdx.y * 128;
  __shared__ __align__(16) short lah[128*32], lal[128*32], lbh[128*32], lbl[128*32];
  int tid = threadIdx.x;
  int w = tid >> 6, lane = tid & 63, l15 = lane & 15, quad = lane >> 4;
  int mbase = (w & 1) * 64, nbase = (w >> 1) * 64;
  f32x4 acc[4][4];
  #pragma unroll
  for (int i = 0; i < 4; i++)
    #pragma unroll
    for (int j = 0; j < 4; j++) acc[i][j] = (f32x4){0.f,0.f,0.f,0.f};
  int sr = w*32 + (lane >> 2);
  int sc = ((lane & 3) ^ (sr & 3)) * 8;
  long gA = (long)(M0 + sr)*768 + sc;
  long gB = (long)(N0 + sr)*768 + sc;
  int swq = (quad ^ (l15 & 3)) * 8;
  for (int k0 = 0; k0 < 768; k0 += 32){
    gl_lds16(Ah + gA + k0,          lah + w*1024);
    gl_lds16(Ah + gA + 16*768 + k0, lah + w*1024 + 512);
    gl_lds16(Al + gA + k0,          lal + w*1024);
    gl_lds16(Al + gA + 16*768 + k0, lal + w*1024 + 512);
    gl_lds16(Bh + gB + k0,          lbh + w*1024);
    gl_lds16(Bh + gB + 16*768 + k0, lbh + w*1024 + 512);
    gl_lds16(Bl + gB + k0,          lbl + w*1024);
    gl_lds16(Bl + gB + 16*768 + k0, lbl + w*1024 + 512);
    __syncthreads();
    bf16x8 afh[4], afl[4];
    #pragma unroll
    for (int mt = 0; mt < 4; mt++){
      afh[mt] = *(const bf16x8*)&lah[(mbase+mt*16+l15)*32 + swq];
      afl[mt] = *(const bf16x8*)&lal[(mbase+mt*16+l15)*32 + swq];
    }
    #pragma unroll
    for (int nt = 0; nt < 4; nt++){
      bf16x8 bfh = *(const bf16x8*)&lbh[(nbase+nt*16+l15)*32 + swq];
      bf16x8 bfl = *(const bf16x8*)&lbl[(nbase+nt*16+l15)*32 + swq];
      #pragma unroll
      for (int mt = 0; mt < 4; mt++){
        acc[mt][nt] = MFMA16(afh[mt], bfh, acc[mt][nt]);
        acc[mt][nt] = MFMA16(afh[mt], bfl, acc[mt][nt]);
        acc[mt][nt] = MFMA16(afl[mt], bfh, acc[mt][nt]);
      }
    }
    __syncthreads();
  }
  #pragma unroll
  for (int mt = 0; mt < 4; mt++)
    #pragma unroll
    for (int nt = 0; nt < 4; nt++)
      #pragma unroll
      for (int rg = 0; rg < 4; rg++){
        int m = M0 + mbase + mt*16 + quad*4 + rg;
        int n = N0 + nbase + nt*16 + l15;
        hout[(long)m*768 + n] = acc[mt][nt][rg] + x[(long)m*768 + n] + bo[n];
      }
}

// ---------------- LN2 + router ----------------
__global__ void k_zero(int* cnt){ if (threadIdx.x < 8) cnt[threadIdx.x] = 0; }

__global__ void k_router(const float* __restrict__ h, const float* __restrict__ g,
                         const float* __restrict__ bb, const float* __restrict__ Wr,
                         const float* __restrict__ br, short* __restrict__ xn2,
                         int* __restrict__ cnt, int* __restrict__ perm,
                         float* __restrict__ gw){
  int t = blockIdx.x, tid = threadIdx.x;
  const float* xr = h + (long)t * 768;
  float v[3];
  #pragma unroll
  for (int j = 0; j < 3; j++) v[j] = xr[tid + 256*j];
  float s = v[0]+v[1]+v[2];
  float q = v[0]*v[0]+v[1]*v[1]+v[2]*v[2];
  #pragma unroll
  for (int o = 32; o > 0; o >>= 1){ s += __shfl_down(s,o,64); q += __shfl_down(q,o,64); }
  __shared__ float ss[4], qs[4];
  __shared__ float lred[4][8];
  int w = tid >> 6;
  if ((tid & 63) == 0){ ss[w] = s; qs[w] = q; }
  __syncthreads();
  float St = ss[0]+ss[1]+ss[2]+ss[3], Qt = qs[0]+qs[1]+qs[2]+qs[3];
  float mean = St * (1.f/768.f);
  float var  = Qt * (1.f/768.f) - mean*mean;
  float inv  = 1.f / sqrtf(var + 1e-5f);
  float part[8] = {0,0,0,0,0,0,0,0};
  #pragma unroll
  for (int j = 0; j < 3; j++){
    int d = tid + 256*j;
    float xn = (v[j]-mean)*inv*g[d] + bb[d];
    xn2[(long)t*768 + d] = f2bf(xn);
    #pragma unroll
    for (int e = 0; e < 8; e++) part[e] += xn * Wr[d*8 + e];
  }
  #pragma unroll
  for (int o = 32; o > 0; o >>= 1)
    #pragma unroll
    for (int e = 0; e < 8; e++) part[e] += __shfl_down(part[e], o, 64);
  if ((tid & 63) == 0)
    #pragma unroll
    for (int e = 0; e < 8; e++) lred[w][e] = part[e];
  __syncthreads();
  if (tid == 0){
    float lg[8];
    #pragma unroll
    for (int e = 0; e < 8; e++) lg[e] = lred[0][e]+lred[1][e]+lred[2][e]+lred[3][e] + br[e];
    int i1 = 0;
    for (int e = 1; e < 8; e++) if (lg[e] > lg[i1]) i1 = e;
    int i2 = -1;
    for (int e = 0; e < 8; e++){ if (e == i1) continue; if (i2 < 0 || lg[e] > lg[i2]) i2 = e; }
    float e2 = expf(lg[i2] - lg[i1]);
    float is = 1.f / (1.f + e2);
    gw[t*2]   = is;
    gw[t*2+1] = e2 * is;
    int p1 = atomicAdd(&cnt[i1], 1); perm[i1*2048 + p1] = t*2;
    int p2 = atomicAdd(&cnt[i2], 1); perm[i2*2048 + p2] = t*2 + 1;
  }
}

// scan with 128-padding: per-expert padded offsets + Mblk counts
__global__ void k_scan(const int* __restrict__ cnt, int* __restrict__ poffs,
                       int* __restrict__ eidx, int* __restrict__ mbc,
                       int* __restrict__ ptot){
  if (threadIdx.x == 0){
    int p = 0;
    for (int e = 0; e < 8; e++){
      poffs[e] = p;
      int pc = (cnt[e] + 127) & ~127;
      mbc[e] = pc >> 7;
      for (int j = p >> 7; j < (p + pc) >> 7; j++) eidx[j] = e;
      p += pc;
    }
    *ptot = p;
    for (int j = p >> 7; j < 40; j++) eidx[j] = 7;
  }
}

// build flat padded slot list (perm value or -1) + inverse map token2slot
__global__ void k_fill(const int* __restrict__ cnt, const int* __restrict__ poffs,
                       const int* __restrict__ eidx, const int* __restrict__ perm,
                       const int* __restrict__ ptot, int* __restrict__ pperm,
                       int* __restrict__ inv){
  int i = blockIdx.x*256 + threadIdx.x;   // 5120
  int e = eidx[i >> 7];
  int li = i - poffs[e];
  int v = -1;
  if (i < *ptot && li >= 0 && li < cnt[e]){ v = perm[e*2048 + li]; inv[v] = i; }
  pperm[i] = v;
}

// ---------------- MoE GEMM1: h1[p] = gelu(xn2[tok(p)] @ W1T[e] + b1) --------
// grid (192 = e*24+n weight-tile [XCD-pinned], 16 = Mblk-within-expert)
__global__ __launch_bounds__(256,3) void k_moe1(
    const short* __restrict__ xn2, const short* __restrict__ W1T,
    const float* __restrict__ b1,
    const int* __restrict__ poffs, const int* __restrict__ mbc,
    const int* __restrict__ pperm, short* __restrict__ h1){
  int t = blockIdx.x;
  int e = t / 24, n = t % 24;
  if ((int)blockIdx.y >= mbc[e]) return;
  int M0 = poffs[e] + blockIdx.y * 128;
  int N0 = n * 128;
  const short* Bp = W1T + (long)e * 3072 * 768;
  __shared__ __align__(16) short la[128*64], lb[128*64];
  __shared__ int rtok[128];
  int tid = threadIdx.x, w = tid >> 6, lane = tid & 63, l15 = lane & 15, quad = lane >> 4;
  if (tid < 128) rtok[tid] = pperm[M0 + tid];
  __syncthreads();
  int rl = lane >> 3, pch = lane & 7;
  long gA[4], gB[4];
  #pragma unroll
  for (int j = 0; j < 4; j++){
    int r = w*32 + j*8 + rl;
    int c = pch ^ (r & 7);
    int tk = rtok[r]; tk = (tk >= 0) ? (tk >> 1) : 0;
    gA[j] = (long)tk*768 + c*8;
    gB[j] = (long)(N0 + r)*768 + c*8;
  }
  short* ldA = la + w*2048;
  short* ldB = lb + w*2048;
  f32x4 acc[4][4];
  #pragma unroll
  for (int i = 0; i < 4; i++)
    #pragma unroll
    for (int j = 0; j < 4; j++) acc[i][j] = (f32x4){0.f,0.f,0.f,0.f};
  int mbase = (w & 1) * 64, nbase = (w >> 1) * 64;
  for (int k0 = 0; k0 < 768; k0 += 64){
    #pragma unroll
    for (int j = 0; j < 4; j++) gl_lds16(xn2 + gA[j] + k0, ldA + j*512);
    #pragma unroll
    for (int j = 0; j < 4; j++) gl_lds16(Bp  + gB[j] + k0, ldB + j*512);
    __syncthreads();
    #pragma unroll
    for (int kk = 0; kk < 2; kk++){
      int swq = ((kk*4 + quad) ^ (l15 & 7)) * 8;
      bf16x8 af[4];
      #pragma unroll
      for (int mt = 0; mt < 4; mt++)
        af[mt] = *(const bf16x8*)&la[(mbase+mt*16+l15)*64 + swq];
      #pragma unroll
      for (int nt = 0; nt < 4; nt++){
        bf16x8 bf = *(const bf16x8*)&lb[(nbase+nt*16+l15)*64 + swq];
        #pragma unroll
        for (int mt = 0; mt < 4; mt++) acc[mt][nt] = MFMA16(af[mt], bf, acc[mt][nt]);
      }
    }
    __syncthreads();
  }
  #pragma unroll
  for (int mt = 0; mt < 4; mt++)
    #pragma unroll
    for (int nt = 0; nt < 4; nt++)
      #pragma unroll
      for (int rg = 0; rg < 4; rg++){
        int ml = mbase + mt*16 + quad*4 + rg;
        if (rtok[ml] >= 0){
          int nn = N0 + nbase + nt*16 + l15;
          float vv = acc[mt][nt][rg] + b1[e*3072 + nn];
          float gl = 0.5f * vv * (1.f + erff(vv * 0.70710678118654752f));
          h1[(long)(M0 + ml)*3072 + nn] = f2bf(gl);
        }
      }
}

// ---------------- MoE GEMM2: E[ks][slot] = h1 @ W2T[e](+b2), split-K=2 ------
// grid (96 = e*12+n*2+ks weight-tile [XCD-pinned], 16 = Mblk-within-expert)
// slot-indexed plain stores -> NO atomics.
__global__ __launch_bounds__(256,3) void k_moe2(
    const short* __restrict__ h1, const short* __restrict__ W2T,
    const float* __restrict__ b2,
    const int* __restrict__ poffs, const int* __restrict__ mbc,
    float* __restrict__ e0, float* __restrict__ e1){
  int t = blockIdx.x;
  int e = t / 12, r12 = t % 12;
  int n = r12 >> 1, ks = r12 & 1;
  if ((int)blockIdx.y >= mbc[e]) return;
  int M0 = poffs[e] + blockIdx.y * 128;
  int N0 = n * 128;
  int kbeg = ks * 1536;
  const short* Bp = W2T + (long)e * 768 * 3072;
  float* eo = ks ? e1 : e0;
  __shared__ __align__(16) short la[128*64], lb[128*64];
  int tid = threadIdx.x, w = tid >> 6, lane = tid & 63, l15 = lane & 15, quad = lane >> 4;
  int rl = lane >> 3, pch = lane & 7;
  long gA[4], gB[4];
  #pragma unroll
  for (int j = 0; j < 4; j++){
    int r = w*32 + j*8 + rl;
    int c = pch ^ (r & 7);
    gA[j] = (long)(M0 + r)*3072 + kbeg + c*8;
    gB[j] = (long)(N0 + r)*3072 + kbeg + c*8;
  }
  short* ldA = la + w*2048;
  short* ldB = lb + w*2048;
  f32x4 acc[4][4];
  #pragma unroll
  for (int i = 0; i < 4; i++)
    #pragma unroll
    for (int j = 0; j < 4; j++) acc[i][j] = (f32x4){0.f,0.f,0.f,0.f};
  int mbase = (w & 1) * 64, nbase = (w >> 1) * 64;
  for (int k0 = 0; k0 < 1536; k0 += 64){
    #pragma unroll
    for (int j = 0; j < 4; j++) gl_lds16(h1 + gA[j] + k0, ldA + j*512);
    #pragma unroll
    for (int j = 0; j < 4; j++) gl_lds16(Bp + gB[j] + k0, ldB + j*512);
    __syncthreads();
    #pragma unroll
    for (int kk = 0; kk < 2; kk++){
      int swq = ((kk*4 + quad) ^ (l15 & 7)) * 8;
      bf16x8 af[4];
      #pragma unroll
      for (int mt = 0; mt < 4; mt++)
        af[mt] = *(const bf16x8*)&la[(mbase+mt*16+l15)*64 + swq];
      #pragma unroll
      for (int nt = 0; nt < 4; nt++){
        bf16x8 bf = *(const bf16x8*)&lb[(nbase+nt*16+l15)*64 + swq];
        #pragma unroll
        for (int mt = 0; mt < 4; mt++) acc[mt][nt] = MFMA16(af[mt], bf, acc[mt][nt]);
      }
    }
    __syncthreads();
  }
  #pragma unroll
  for (int mt = 0; mt < 4; mt++)
    #pragma unroll
    for (int nt = 0; nt < 4; nt++)
      #pragma unroll
      for (int rg = 0; rg < 4; rg++){
        int ml = mbase + mt*16 + quad*4 + rg;
        int nn = N0 + nbase + nt*16 + l15;
        float vv = acc[mt][nt][rg] + (ks ? 0.f : b2[e*768 + nn]);
        eo[(long)(M0 + ml)*768 + nn] = vv;
      }
}

// ---------------- final combine: out = h + g0*(E0+E1)[s0] + g1*(E0+E1)[s1] --
__global__ void k_combine(const float* __restrict__ h,
                          const float* __restrict__ e0, const float* __restrict__ e1,
                          const int* __restrict__ inv, const float* __restrict__ gw,
                          float* __restrict__ out){
  int i = blockIdx.x * 256 + threadIdx.x;     // 393216 float4s
  int t = i / 192, c = i - t * 192;
  int s0 = inv[2*t], s1 = inv[2*t+1];
  float g0 = gw[2*t], g1 = gw[2*t+1];
  float4 a  = ((const float4*)h)[i];
  float4 x0 = ((const float4*)e0)[(long)s0*192 + c];
  float4 y0 = ((const float4*)e1)[(long)s0*192 + c];
  float4 x1 = ((const float4*)e0)[(long)s1*192 + c];
  float4 y1 = ((const float4*)e1)[(long)s1*192 + c];
  float4 o;
  o.x = a.x + g0*(x0.x + y0.x) + g1*(x1.x + y1.x);
  o.y = a.y + g0*(x0.y + y0.y) + g1*(x1.y + y1.y);
  o.z = a.z + g0*(x0.z + y0.z) + g1*(x1.z + y1.z);
  o.w = a.w + g0*(x0.w + y0.w) + g1*(x1.w + y1.w);
  ((float4*)out)[i] = o;
}

// ---------------- launcher ----------------
extern "C" void kernel_launch(void* const* d_in, const int* in_sizes, int n_in,
                              void* d_out, int out_size, void* d_ws, size_t ws_size,
                              hipStream_t stream){
  const float* x    = (const float*)d_in[0];
  const float* ln1g = (const float*)d_in[1];
  const float* ln1b = (const float*)d_in[2];
  const float* Wq   = (const float*)d_in[3];
  const float* Wk   = (const float*)d_in[4];
  const float* Wv   = (const float*)d_in[5];
  const float* Wo   = (const float*)d_in[6];
  const float* bo   = (const float*)d_in[7];
  const float* ln2g = (const float*)d_in[8];
  const float* ln2b = (const float*)d_in[9];
  const float* Wr   = (const float*)d_in[10];
  const float* br   = (const float*)d_in[11];
  const float* W1   = (const float*)d_in[12];
  const float* b1   = (const float*)d_in[13];
  const float* W2   = (const float*)d_in[14];
  const float* b2   = (const float*)d_in[15];

  char* ws = (char*)d_ws;
  size_t off = 0;
  auto alloc = [&](size_t bytes) -> void* {
    void* p = ws + off;
    off += (bytes + 255) & ~(size_t)255;
    return p;
  };
  short* WQKVH = (short*)alloc(2304l*768*2);
  short* WQKVL = (short*)alloc(2304l*768*2);
  short* WOH   = (short*)alloc(768l*768*2);
  short* WOL   = (short*)alloc(768l*768*2);
  short* W1T   = (short*)alloc(8l*3072*768*2);
  short* W2T   = (short*)alloc(8l*768*3072*2);
  short* XN1H  = (short*)alloc(2048l*768*2);
  short* XN1L  = (short*)alloc(2048l*768*2);
  short* QH    = (short*)alloc(2048l*768*2);
  short* QL    = (short*)alloc(2048l*768*2);
  short* KH    = (short*)alloc(2048l*768*2);
  short* KL    = (short*)alloc(2048l*768*2);
  short* VTH   = (short*)alloc(2048l*768*2);
  short* VTL   = (short*)alloc(2048l*768*2);
  short* ATH   = (short*)alloc(2048l*768*2);
  short* ATL   = (short*)alloc(2048l*768*2);
  float* HBUF  = (float*)alloc(2048l*768*4);
  short* XN2   = (short*)alloc(2048l*768*2);
  short* H1    = (short*)alloc(5120l*3072*2);
  float* E0    = (float*)alloc(5120l*768*4);
  float* E1    = (float*)alloc(5120l*768*4);
  float* PO    = (float*)alloc(2l*24*1024*64*4);
  float* PM    = (float*)alloc(2l*24*1024*4);
  float* PL    = (float*)alloc(2l*24*1024*4);
  int*   CNT   = (int*)alloc(8*4);
  int*   POFF  = (int*)alloc(8*4);
  int*   EIDX  = (int*)alloc(40*4);
  int*   MBC   = (int*)alloc(8*4);
  int*   PTOT  = (int*)alloc(4);
  int*   PERM  = (int*)alloc(8l*2048*4);
  int*   PPERM = (int*)alloc(5120*4);
  int*   INV   = (int*)alloc(4096*4);
  float* GW    = (float*)alloc(4096*4);
  (void)ws_size; (void)in_sizes; (void)n_in; (void)out_size;

  // weight prep (transpose + bf16 hi/lo split)
  k_transpose<<<dim3(24,24,1),256,0,stream>>>(Wq, 0, WQKVH,             WQKVL,             0, 768, 768);
  k_transpose<<<dim3(24,24,1),256,0,stream>>>(Wk, 0, WQKVH + 768l*768,  WQKVL + 768l*768,  0, 768, 768);
  k_transpose<<<dim3(24,24,1),256,0,stream>>>(Wv, 0, WQKVH + 1536l*768, WQKVL + 1536l*768, 0, 768, 768);
  k_transpose<<<dim3(24,24,1),256,0,stream>>>(Wo, 0, WOH, WOL, 0, 768, 768);
  k_transpose<<<dim3(96,24,8),256,0,stream>>>(W1, 768l*3072, W1T, nullptr, 3072l*768, 768, 3072);
  k_transpose<<<dim3(24,96,8),256,0,stream>>>(W2, 3072l*768, W2T, nullptr, 768l*3072, 3072, 768);

  // attention path (split-bf16 precision)
  k_ln1<<<2048,256,0,stream>>>(x, ln1g, ln1b, XN1H, XN1L);
  k_qkv<<<dim3(16,18),256,0,stream>>>(XN1H, XN1L, WQKVH, WQKVL, QH, QL, KH, KL, VTH, VTL);
  k_attn<<<dim3(32,24),256,0,stream>>>(QH, QL, KH, KL, VTH, VTL, PO, PM, PL);
  k_attn_combine<<<dim3(16,24),256,0,stream>>>(PO, PM, PL, ATH, ATL);
  k_wo<<<dim3(16,6),256,0,stream>>>(ATH, ATL, WOH, WOL, x, bo, HBUF);

  // router + MoE
  k_zero<<<1,64,0,stream>>>(CNT);
  k_router<<<2048,256,0,stream>>>(HBUF, ln2g, ln2b, Wr, br, XN2, CNT, PERM, GW);
  k_scan<<<1,64,0,stream>>>(CNT, POFF, EIDX, MBC, PTOT);
  k_fill<<<20,256,0,stream>>>(CNT, POFF, EIDX, PERM, PTOT, PPERM, INV);
  k_moe1<<<dim3(192,16),256,0,stream>>>(XN2, W1T, b1, POFF, MBC, PPERM, H1);
  k_moe2<<<dim3(96,16),256,0,stream>>>(H1, W2T, b2, POFF, MBC, E0, E1);
  k_combine<<<1536,256,0,stream>>>(HBUF, E0, E1, INV, GW, (float*)d_out);
}

// Round 6
// 467.777 us; speedup vs baseline: 1.2191x; 1.0941x over previous
//
#include <hip/hip_runtime.h>

// ---------------- common helpers ----------------
using bf16x8 = __attribute__((ext_vector_type(8))) short;
using f32x4  = __attribute__((ext_vector_type(4))) float;

#define DEV __device__ __forceinline__

DEV short f2bf(float x){
  unsigned u = __float_as_uint(x);
  u += 0x7fffu + ((u >> 16) & 1u);
  return (short)(u >> 16);
}
DEV float bf2f(short h){ return __uint_as_float(((unsigned)(unsigned short)h) << 16); }

#define MFMA16(a,b,c) __builtin_amdgcn_mfma_f32_16x16x32_bf16(a,b,c,0,0,0)

// async global->LDS, 16B per lane; LDS dest is wave-uniform base + lane*16
DEV void gl_lds16(const void* g, void* l){
  __builtin_amdgcn_global_load_lds(
      (const __attribute__((address_space(1))) unsigned*)g,
      (__attribute__((address_space(3))) unsigned*)l, 16, 0, 0);
}

// Problem constants: B=2 S=1024 D=768 H=12 HD=64 E=8 DF=3072 K=2, T=2048

// ---------------- transpose + fp32->bf16(hi/lo) convert ----------------
__global__ void k_transpose(const float* __restrict__ src, long sbatch,
                            short* __restrict__ dhi, short* __restrict__ dlo, long dbatch,
                            int R, int C){
  __shared__ float tile[32][33];
  const float* s = src + (long)blockIdx.z * sbatch;
  int c0 = blockIdx.x * 32, r0 = blockIdx.y * 32;
  int tx = threadIdx.x & 31, ty = threadIdx.x >> 5;   // 32x8
  #pragma unroll
  for (int i = 0; i < 4; i++)
    tile[ty + 8*i][tx] = s[(long)(r0 + ty + 8*i) * C + c0 + tx];
  __syncthreads();
  #pragma unroll
  for (int i = 0; i < 4; i++){
    int c = c0 + ty + 8*i;
    float v = tile[tx][ty + 8*i];
    short hv = f2bf(v);
    long o = (long)blockIdx.z * dbatch + (long)c * R + r0 + tx;
    dhi[o] = hv;
    if (dlo) dlo[o] = f2bf(v - bf2f(hv));
  }
}

// ---------------- LayerNorm1: x -> xn1 hi/lo bf16 ----------------
__global__ void k_ln1(const float* __restrict__ x, const float* __restrict__ g,
                      const float* __restrict__ bb,
                      short* __restrict__ xh, short* __restrict__ xl){
  int t = blockIdx.x, tid = threadIdx.x;
  const float* xr = x + (long)t * 768;
  float v[3];
  #pragma unroll
  for (int j = 0; j < 3; j++) v[j] = xr[tid + 256*j];
  float s = v[0]+v[1]+v[2];
  float q = v[0]*v[0]+v[1]*v[1]+v[2]*v[2];
  #pragma unroll
  for (int o = 32; o > 0; o >>= 1){ s += __shfl_down(s,o,64); q += __shfl_down(q,o,64); }
  __shared__ float ss[4], qs[4];
  int w = tid >> 6;
  if ((tid & 63) == 0){ ss[w] = s; qs[w] = q; }
  __syncthreads();
  float St = ss[0]+ss[1]+ss[2]+ss[3], Qt = qs[0]+qs[1]+qs[2]+qs[3];
  float mean = St * (1.f/768.f);
  float var  = Qt * (1.f/768.f) - mean*mean;
  float inv  = 1.f / sqrtf(var + 1e-5f);
  #pragma unroll
  for (int j = 0; j < 3; j++){
    int d = tid + 256*j;
    float xn = (v[j]-mean)*inv*g[d] + bb[d];
    short hv = f2bf(xn);
    xh[(long)t*768 + d] = hv;
    xl[(long)t*768 + d] = f2bf(xn - bf2f(hv));
  }
}

// ---------------- split-bf16 GEMM: qkv = xn1 @ Wqkv (BK=64, gl_lds) --------
__global__ __launch_bounds__(256,2) void k_qkv(
    const short* __restrict__ Ah, const short* __restrict__ Al,
    const short* __restrict__ Bh, const short* __restrict__ Bl,
    short* __restrict__ qh, short* __restrict__ ql,
    short* __restrict__ kh, short* __restrict__ kl,
    short* __restrict__ vh, short* __restrict__ vl){
  int M0 = blockIdx.x * 128, N0 = blockIdx.y * 128;
  __shared__ __align__(16) short lah[128*64], lal[128*64], lbh[128*64], lbl[128*64];
  int tid = threadIdx.x;
  int w = tid >> 6, lane = tid & 63, l15 = lane & 15, quad = lane >> 4;
  int mbase = (w & 1) * 64, nbase = (w >> 1) * 64;
  f32x4 acc[4][4];
  #pragma unroll
  for (int i = 0; i < 4; i++)
    #pragma unroll
    for (int j = 0; j < 4; j++) acc[i][j] = (f32x4){0.f,0.f,0.f,0.f};
  int rl = lane >> 3, pch = lane & 7;
  long gA[4], gB[4];
  #pragma unroll
  for (int j = 0; j < 4; j++){
    int r = w*32 + j*8 + rl;
    int c = pch ^ (r & 7);
    gA[j] = (long)(M0 + r)*768 + c*8;
    gB[j] = (long)(N0 + r)*768 + c*8;
  }
  for (int k0 = 0; k0 < 768; k0 += 64){
    #pragma unroll
    for (int j = 0; j < 4; j++){
      gl_lds16(Ah + gA[j] + k0, lah + w*2048 + j*512);
      gl_lds16(Al + gA[j] + k0, lal + w*2048 + j*512);
      gl_lds16(Bh + gB[j] + k0, lbh + w*2048 + j*512);
      gl_lds16(Bl + gB[j] + k0, lbl + w*2048 + j*512);
    }
    __syncthreads();
    #pragma unroll
    for (int kk = 0; kk < 2; kk++){
      int swq = ((kk*4 + quad) ^ (l15 & 7)) * 8;
      bf16x8 afh[4], afl[4];
      #pragma unroll
      for (int mt = 0; mt < 4; mt++){
        afh[mt] = *(const bf16x8*)&lah[(mbase+mt*16+l15)*64 + swq];
        afl[mt] = *(const bf16x8*)&lal[(mbase+mt*16+l15)*64 + swq];
      }
      #pragma unroll
      for (int nt = 0; nt < 4; nt++){
        bf16x8 bfh = *(const bf16x8*)&lbh[(nbase+nt*16+l15)*64 + swq];
        bf16x8 bfl = *(const bf16x8*)&lbl[(nbase+nt*16+l15)*64 + swq];
        #pragma unroll
        for (int mt = 0; mt < 4; mt++){
          acc[mt][nt] = MFMA16(afh[mt], bfh, acc[mt][nt]);
          acc[mt][nt] = MFMA16(afh[mt], bfl, acc[mt][nt]);
          acc[mt][nt] = MFMA16(afl[mt], bfh, acc[mt][nt]);
        }
      }
    }
    __syncthreads();
  }
  // epilogue: scatter into q[bh][s][hd], k[bh][s][hd], vT[bh][hd][s]
  #pragma unroll
  for (int mt = 0; mt < 4; mt++){
    #pragma unroll
    for (int nt = 0; nt < 4; nt++){
      #pragma unroll
      for (int rg = 0; rg < 4; rg++){
        int m = M0 + mbase + mt*16 + quad*4 + rg;
        int n = N0 + nbase + nt*16 + l15;
        float vv = acc[mt][nt][rg];
        int bi = m >> 10, si = m & 1023;
        if (n < 768){
          float sv = vv * 0.125f;              // fold 1/sqrt(HD)
          short hv = f2bf(sv);
          int hh = n >> 6, hd = n & 63;
          long o = (((long)(bi*12+hh)*1024) + si)*64 + hd;
          qh[o] = hv; ql[o] = f2bf(sv - bf2f(hv));
        } else if (n < 1536){
          int n2 = n - 768;
          short hv = f2bf(vv);
          int hh = n2 >> 6, hd = n2 & 63;
          long o = (((long)(bi*12+hh)*1024) + si)*64 + hd;
          kh[o] = hv; kl[o] = f2bf(vv - bf2f(hv));
        } else {
          int n2 = n - 1536;
          short hv = f2bf(vv);
          int hh = n2 >> 6, hd = n2 & 63;
          long o = (((long)(bi*12+hh)*64) + hd)*1024 + si;
          vh[o] = hv; vl[o] = f2bf(vv - bf2f(hv));
        }
      }
    }
  }
}

// ---------------- flash attention, split-bf16, causal, split-K=2 ------------
__global__ __launch_bounds__(256,3) void k_attn(
    const short* __restrict__ qh, const short* __restrict__ ql,
    const short* __restrict__ kh, const short* __restrict__ kl,
    const short* __restrict__ vth, const short* __restrict__ vtl,
    float* __restrict__ po, float* __restrict__ pm, float* __restrict__ pl){
  int qt = blockIdx.x >> 1, half = blockIdx.x & 1, bh = blockIdx.y;
  int q0 = qt * 64;
  long base = (long)bh * 1024 * 64;
  int ktb = half ? ((qt + 2) >> 1) : 0;
  int kte = half ? (qt + 1) : ((qt + 2) >> 1);
  __shared__ __align__(16) short skh[64*64], skl[64*64], svh[64*64], svl[64*64];
  __shared__ __align__(16) short sph[4][16*72], spl[4][16*72];
  int tid = threadIdx.x, w = tid >> 6, lane = tid & 63, l15 = lane & 15, quad = lane >> 4;
  bf16x8 qfh[2], qfl[2];
  #pragma unroll
  for (int c = 0; c < 2; c++){
    long qa = base + (long)(q0 + w*16 + l15)*64 + c*32 + quad*8;
    qfh[c] = *(const bf16x8*)(qh + qa);
    qfl[c] = *(const bf16x8*)(ql + qa);
  }
  f32x4 oacc[4];
  #pragma unroll
  for (int i = 0; i < 4; i++) oacc[i] = (f32x4){0.f,0.f,0.f,0.f};
  float m_i[4] = {-1e30f,-1e30f,-1e30f,-1e30f};
  float l_i[4] = {0.f,0.f,0.f,0.f};
  const short* gsrc = (w==0) ? kh : (w==1) ? kl : (w==2) ? vth : vtl;
  short* myb = (w==0) ? skh : (w==1) ? skl : (w==2) ? svh : svl;
  bool isv = (w >= 2);
  int rloc = lane >> 3, pch = lane & 7;
  for (int kt = ktb; kt < kte; kt++){
    #pragma unroll
    for (int j = 0; j < 8; j++){
      int r = j*8 + rloc;
      int c = pch ^ (r & 7);
      long ga = isv ? (base + (long)r*1024 + kt*64 + c*8)
                    : (base + (long)(kt*64 + r)*64 + c*8);
      gl_lds16(gsrc + ga, myb + j*512);
    }
    __syncthreads();
    f32x4 sfr[4];
    #pragma unroll
    for (int nt = 0; nt < 4; nt++){
      f32x4 c = (f32x4){0.f,0.f,0.f,0.f};
      int krow = (nt*16 + l15) * 64;
      #pragma unroll
      for (int ch = 0; ch < 2; ch++){
        int pc = ((ch*4 + quad) ^ (l15 & 7)) * 8;
        bf16x8 kfh = *(const bf16x8*)&skh[krow + pc];
        bf16x8 kfl = *(const bf16x8*)&skl[krow + pc];
        c = MFMA16(qfh[ch], kfh, c);
        c = MFMA16(qfh[ch], kfl, c);
        c = MFMA16(qfl[ch], kfh, c);
      }
      sfr[nt] = c;
    }
    if (kt == qt){
      #pragma unroll
      for (int nt = 0; nt < 4; nt++)
        #pragma unroll
        for (int rg = 0; rg < 4; rg++){
          int kp = nt*16 + l15, qp = w*16 + quad*4 + rg;
          if (kp > qp) sfr[nt][rg] = -1e30f;
        }
    }
    float rmax[4];
    #pragma unroll
    for (int rg = 0; rg < 4; rg++)
      rmax[rg] = fmaxf(fmaxf(sfr[0][rg], sfr[1][rg]), fmaxf(sfr[2][rg], sfr[3][rg]));
    #pragma unroll
    for (int xm = 1; xm < 16; xm <<= 1)
      #pragma unroll
      for (int rg = 0; rg < 4; rg++)
        rmax[rg] = fmaxf(rmax[rg], __shfl_xor(rmax[rg], xm, 64));
    float alpha[4];
    #pragma unroll
    for (int rg = 0; rg < 4; rg++){
      float mn = fmaxf(m_i[rg], rmax[rg]);
      alpha[rg] = expf(m_i[rg] - mn);
      m_i[rg] = mn;
    }
    float rsum[4] = {0.f,0.f,0.f,0.f};
    #pragma unroll
    for (int nt = 0; nt < 4; nt++)
      #pragma unroll
      for (int rg = 0; rg < 4; rg++){
        float p = expf(sfr[nt][rg] - m_i[rg]);
        sfr[nt][rg] = p; rsum[rg] += p;
      }
    #pragma unroll
    for (int xm = 1; xm < 16; xm <<= 1)
      #pragma unroll
      for (int rg = 0; rg < 4; rg++)
        rsum[rg] += __shfl_xor(rsum[rg], xm, 64);
    #pragma unroll
    for (int rg = 0; rg < 4; rg++) l_i[rg] = l_i[rg]*alpha[rg] + rsum[rg];
    #pragma unroll
    for (int hd = 0; hd < 4; hd++)
      #pragma unroll
      for (int rg = 0; rg < 4; rg++) oacc[hd][rg] *= alpha[rg];
    #pragma unroll
    for (int nt = 0; nt < 4; nt++)
      #pragma unroll
      for (int rg = 0; rg < 4; rg++){
        float p = sfr[nt][rg];
        short hv = f2bf(p);
        sph[w][(quad*4+rg)*72 + nt*16 + l15] = hv;
        spl[w][(quad*4+rg)*72 + nt*16 + l15] = f2bf(p - bf2f(hv));
      }
    bf16x8 pfh[2], pfl[2];
    #pragma unroll
    for (int ch = 0; ch < 2; ch++){
      pfh[ch] = *(const bf16x8*)&sph[w][l15*72 + ch*32 + quad*8];
      pfl[ch] = *(const bf16x8*)&spl[w][l15*72 + ch*32 + quad*8];
    }
    #pragma unroll
    for (int hd = 0; hd < 4; hd++){
      int vrow = (hd*16 + l15) * 64;
      #pragma unroll
      for (int ch = 0; ch < 2; ch++){
        int pc = ((ch*4 + quad) ^ (l15 & 7)) * 8;
        bf16x8 vfh = *(const bf16x8*)&svh[vrow + pc];
        bf16x8 vfl = *(const bf16x8*)&svl[vrow + pc];
        oacc[hd] = MFMA16(pfh[ch], vfh, oacc[hd]);
        oacc[hd] = MFMA16(pfh[ch], vfl, oacc[hd]);
        oacc[hd] = MFMA16(pfl[ch], vfh, oacc[hd]);
      }
    }
    __syncthreads();
  }
  long pb = ((long)(half*24 + bh)*1024);
  #pragma unroll
  for (int hdt = 0; hdt < 4; hdt++)
    #pragma unroll
    for (int rg = 0; rg < 4; rg++){
      int qp = q0 + w*16 + quad*4 + rg;
      po[(pb + qp)*64 + hdt*16 + l15] = oacc[hdt][rg];
    }
  if (l15 == 0){
    #pragma unroll
    for (int rg = 0; rg < 4; rg++){
      int qp = q0 + w*16 + quad*4 + rg;
      pm[pb + qp] = m_i[rg];
      pl[pb + qp] = l_i[rg];
    }
  }
}

// ---------------- attention combine: merge 2 partials -> bf16 hi/lo ---------
__global__ void k_attn_combine(const float* __restrict__ po, const float* __restrict__ pm,
                               const float* __restrict__ pl,
                               short* __restrict__ oh, short* __restrict__ ol){
  int bh = blockIdx.y, tid = threadIdx.x;
  int r = blockIdx.x*64 + (tid >> 2);
  int c0 = (tid & 3) * 16;
  long i0 = (long)bh*1024 + r;
  long i1 = (long)(24 + bh)*1024 + r;
  float m0 = pm[i0], m1 = pm[i1], l0 = pl[i0], l1 = pl[i1];
  float m = fmaxf(m0, m1);
  float a0 = expf(m0 - m), a1 = expf(m1 - m);
  float inv = 1.f / (a0*l0 + a1*l1);
  a0 *= inv; a1 *= inv;
  int b = bh / 12, hh = bh % 12;
  long ob = ((long)(b*1024 + r))*768 + hh*64 + c0;
  short hv[16], lv[16];
  #pragma unroll
  for (int j = 0; j < 4; j++){
    float4 o0 = *(const float4*)&po[i0*64 + c0 + j*4];
    float4 o1 = *(const float4*)&po[i1*64 + c0 + j*4];
    float vs[4] = {a0*o0.x + a1*o1.x, a0*o0.y + a1*o1.y,
                   a0*o0.z + a1*o1.z, a0*o0.w + a1*o1.w};
    #pragma unroll
    for (int q = 0; q < 4; q++){
      short h = f2bf(vs[q]);
      hv[j*4+q] = h; lv[j*4+q] = f2bf(vs[q] - bf2f(h));
    }
  }
  *(bf16x8*)(oh + ob)     = *(bf16x8*)&hv[0];
  *(bf16x8*)(oh + ob + 8) = *(bf16x8*)&hv[8];
  *(bf16x8*)(ol + ob)     = *(bf16x8*)&lv[0];
  *(bf16x8*)(ol + ob + 8) = *(bf16x8*)&lv[8];
}

// ---------------- split GEMM Wo + residual -> h fp32 (BK=64, gl_lds) -------
__global__ __launch_bounds__(256,2) void k_wo(
    const short* __restrict__ Ah, const short* __restrict__ Al,
    const short* __restrict__ Bh, const short* __restrict__ Bl,
    const float* __restrict__ x, const float* __restrict__ bo,
    float* __restrict__ hout){
  int M0 = blockIdx.x * 128, N0 = blockIdx.y * 128;
  __shared__ __align__(16) short lah[128*64], lal[128*64], lbh[128*64], lbl[128*64];
  int tid = threadIdx.x;
  int w = tid >> 6, lane = tid & 63, l15 = lane & 15, quad = lane >> 4;
  int mbase = (w & 1) * 64, nbase = (w >> 1) * 64;
  f32x4 acc[4][4];
  #pragma unroll
  for (int i = 0; i < 4; i++)
    #pragma unroll
    for (int j = 0; j < 4; j++) acc[i][j] = (f32x4){0.f,0.f,0.f,0.f};
  int rl = lane >> 3, pch = lane & 7;
  long gA[4], gB[4];
  #pragma unroll
  for (int j = 0; j < 4; j++){
    int r = w*32 + j*8 + rl;
    int c = pch ^ (r & 7);
    gA[j] = (long)(M0 + r)*768 + c*8;
    gB[j] = (long)(N0 + r)*768 + c*8;
  }
  for (int k0 = 0; k0 < 768; k0 += 64){
    #pragma unroll
    for (int j = 0; j < 4; j++){
      gl_lds16(Ah + gA[j] + k0, lah + w*2048 + j*512);
      gl_lds16(Al + gA[j] + k0, lal + w*2048 + j*512);
      gl_lds16(Bh + gB[j] + k0, lbh + w*2048 + j*512);
      gl_lds16(Bl + gB[j] + k0, lbl + w*2048 + j*512);
    }
    __syncthreads();
    #pragma unroll
    for (int kk = 0; kk < 2; kk++){
      int swq = ((kk*4 + quad) ^ (l15 & 7)) * 8;
      bf16x8 afh[4], afl[4];
      #pragma unroll
      for (int mt = 0; mt < 4; mt++){
        afh[mt] = *(const bf16x8*)&lah[(mbase+mt*16+l15)*64 + swq];
        afl[mt] = *(const bf16x8*)&lal[(mbase+mt*16+l15)*64 + swq];
      }
      #pragma unroll
      for (int nt = 0; nt < 4; nt++){
        bf16x8 bfh = *(const bf16x8*)&lbh[(nbase+nt*16+l15)*64 + swq];
        bf16x8 bfl = *(const bf16x8*)&lbl[(nbase+nt*16+l15)*64 + swq];
        #pragma unroll
        for (int mt = 0; mt < 4; mt++){
          acc[mt][nt] = MFMA16(afh[mt], bfh, acc[mt][nt]);
          acc[mt][nt] = MFMA16(afh[mt], bfl, acc[mt][nt]);
          acc[mt][nt] = MFMA16(afl[mt], bfh, acc[mt][nt]);
        }
      }
    }
    __syncthreads();
  }
  #pragma unroll
  for (int mt = 0; mt < 4; mt++)
    #pragma unroll
    for (int nt = 0; nt < 4; nt++)
      #pragma unroll
      for (int rg = 0; rg < 4; rg++){
        int m = M0 + mbase + mt*16 + quad*4 + rg;
        int n = N0 + nbase + nt*16 + l15;
        hout[(long)m*768 + n] = acc[mt][nt][rg] + x[(long)m*768 + n] + bo[n];
      }
}

// ---------------- LN2 + router: wave-per-token, NO global atomics -----------
// grid 256 x 256thr; wave wv handles tokens wv*2, wv*2+1
__global__ void k_ln2router(const float* __restrict__ h, const float* __restrict__ g,
                            const float* __restrict__ bb, const float* __restrict__ Wr,
                            const float* __restrict__ br, short* __restrict__ xn2,
                            int* __restrict__ sel, float* __restrict__ gw){
  int wv = (blockIdx.x*256 + threadIdx.x) >> 6;
  int lane = threadIdx.x & 63;
  #pragma unroll
  for (int rep = 0; rep < 2; rep++){
    int t = wv*2 + rep;
    const float* xr = h + (long)t * 768;
    float v[12];
    #pragma unroll
    for (int j = 0; j < 12; j++) v[j] = xr[lane + 64*j];
    float s = 0.f, q = 0.f;
    #pragma unroll
    for (int j = 0; j < 12; j++){ s += v[j]; q += v[j]*v[j]; }
    #pragma unroll
    for (int xm = 1; xm < 64; xm <<= 1){ s += __shfl_xor(s, xm, 64); q += __shfl_xor(q, xm, 64); }
    float mean = s * (1.f/768.f);
    float var  = q * (1.f/768.f) - mean*mean;
    float inv  = 1.f / sqrtf(var + 1e-5f);
    float part[8] = {0,0,0,0,0,0,0,0};
    #pragma unroll
    for (int j = 0; j < 12; j++){
      int d = lane + 64*j;
      float xn = (v[j]-mean)*inv*g[d] + bb[d];
      xn2[(long)t*768 + d] = f2bf(xn);
      #pragma unroll
      for (int e = 0; e < 8; e++) part[e] += xn * Wr[d*8 + e];
    }
    #pragma unroll
    for (int xm = 1; xm < 64; xm <<= 1)
      #pragma unroll
      for (int e = 0; e < 8; e++) part[e] += __shfl_xor(part[e], xm, 64);
    if (lane == 0){
      float lg[8];
      #pragma unroll
      for (int e = 0; e < 8; e++) lg[e] = part[e] + br[e];
      int i1 = 0;
      for (int e = 1; e < 8; e++) if (lg[e] > lg[i1]) i1 = e;
      int i2 = -1;
      for (int e = 0; e < 8; e++){ if (e == i1) continue; if (i2 < 0 || lg[e] > lg[i2]) i2 = e; }
      float e2 = expf(lg[i2] - lg[i1]);
      float is = 1.f / (1.f + e2);
      gw[t*2]   = is;
      gw[t*2+1] = e2 * is;
      sel[t*2]   = i1;
      sel[t*2+1] = i2;
    }
  }
}

// single-block compaction: histogram + padded offsets + placement (LDS atomics)
__global__ void k_build(const int* __restrict__ sel, int* __restrict__ poffs,
                        int* __restrict__ mbc, int* __restrict__ ptot,
                        int* __restrict__ pperm, int* __restrict__ inv){
  __shared__ int cnt8[8], cur[8];
  int tid = threadIdx.x;   // 1024
  if (tid < 8) cnt8[tid] = 0;
  __syncthreads();
  #pragma unroll
  for (int r = 0; r < 4; r++) atomicAdd(&cnt8[sel[tid + r*1024]], 1);
  __syncthreads();
  if (tid == 0){
    int p = 0;
    for (int e = 0; e < 8; e++){
      cur[e] = p; poffs[e] = p;
      int pc = (cnt8[e] + 127) & ~127;
      mbc[e] = pc >> 7;
      p += pc;
    }
    *ptot = p;
  }
  __syncthreads();
  #pragma unroll
  for (int r = 0; r < 5; r++) pperm[tid + r*1024] = -1;
  __syncthreads();
  #pragma unroll
  for (int r = 0; r < 4; r++){
    int i = tid + r*1024;
    int pos = atomicAdd(&cur[sel[i]], 1);
    pperm[pos] = i;
    inv[i] = pos;
  }
}

// ---------------- MoE GEMM1: h1[p] = gelu(xn2[tok(p)] @ W1T[e] + b1) --------
// grid (192 = e*24+n weight-tile [XCD-pinned], 16 = Mblk-within-expert)
__global__ __launch_bounds__(256,3) void k_moe1(
    const short* __restrict__ xn2, const short* __restrict__ W1T,
    const float* __restrict__ b1,
    const int* __restrict__ poffs, const int* __restrict__ mbc,
    const int* __restrict__ pperm, short* __restrict__ h1){
  int t = blockIdx.x;
  int e = t / 24, n = t % 24;
  if ((int)blockIdx.y >= mbc[e]) return;
  int M0 = poffs[e] + blockIdx.y * 128;
  int N0 = n * 128;
  const short* Bp = W1T + (long)e * 3072 * 768;
  __shared__ __align__(16) short la[128*64], lb[128*64];
  __shared__ int rtok[128];
  int tid = threadIdx.x, w = tid >> 6, lane = tid & 63, l15 = lane & 15, quad = lane >> 4;
  if (tid < 128) rtok[tid] = pperm[M0 + tid];
  __syncthreads();
  int rl = lane >> 3, pch = lane & 7;
  long gA[4], gB[4];
  #pragma unroll
  for (int j = 0; j < 4; j++){
    int r = w*32 + j*8 + rl;
    int c = pch ^ (r & 7);
    int tk = rtok[r]; tk = (tk >= 0) ? (tk >> 1) : 0;
    gA[j] = (long)tk*768 + c*8;
    gB[j] = (long)(N0 + r)*768 + c*8;
  }
  short* ldA = la + w*2048;
  short* ldB = lb + w*2048;
  f32x4 acc[4][4];
  #pragma unroll
  for (int i = 0; i < 4; i++)
    #pragma unroll
    for (int j = 0; j < 4; j++) acc[i][j] = (f32x4){0.f,0.f,0.f,0.f};
  int mbase = (w & 1) * 64, nbase = (w >> 1) * 64;
  for (int k0 = 0; k0 < 768; k0 += 64){
    #pragma unroll
    for (int j = 0; j < 4; j++) gl_lds16(xn2 + gA[j] + k0, ldA + j*512);
    #pragma unroll
    for (int j = 0; j < 4; j++) gl_lds16(Bp  + gB[j] + k0, ldB + j*512);
    __syncthreads();
    #pragma unroll
    for (int kk = 0; kk < 2; kk++){
      int swq = ((kk*4 + quad) ^ (l15 & 7)) * 8;
      bf16x8 af[4];
      #pragma unroll
      for (int mt = 0; mt < 4; mt++)
        af[mt] = *(const bf16x8*)&la[(mbase+mt*16+l15)*64 + swq];
      #pragma unroll
      for (int nt = 0; nt < 4; nt++){
        bf16x8 bf = *(const bf16x8*)&lb[(nbase+nt*16+l15)*64 + swq];
        #pragma unroll
        for (int mt = 0; mt < 4; mt++) acc[mt][nt] = MFMA16(af[mt], bf, acc[mt][nt]);
      }
    }
    __syncthreads();
  }
  #pragma unroll
  for (int mt = 0; mt < 4; mt++)
    #pragma unroll
    for (int nt = 0; nt < 4; nt++)
      #pragma unroll
      for (int rg = 0; rg < 4; rg++){
        int ml = mbase + mt*16 + quad*4 + rg;
        if (rtok[ml] >= 0){
          int nn = N0 + nbase + nt*16 + l15;
          float vv = acc[mt][nt][rg] + b1[e*3072 + nn];
          float gl = 0.5f * vv * (1.f + erff(vv * 0.70710678118654752f));
          h1[(long)(M0 + ml)*3072 + nn] = f2bf(gl);
        }
      }
}

// ---------------- MoE GEMM2: E[ks][slot] = h1 @ W2T[e](+b2), split-K=2 ------
// grid (96 = e*12+n*2+ks weight-tile [XCD-pinned], 16 = Mblk-within-expert)
__global__ __launch_bounds__(256,3) void k_moe2(
    const short* __restrict__ h1, const short* __restrict__ W2T,
    const float* __restrict__ b2,
    const int* __restrict__ poffs, const int* __restrict__ mbc,
    float* __restrict__ e0, float* __restrict__ e1){
  int t = blockIdx.x;
  int e = t / 12, r12 = t % 12;
  int n = r12 >> 1, ks = r12 & 1;
  if ((int)blockIdx.y >= mbc[e]) return;
  int M0 = poffs[e] + blockIdx.y * 128;
  int N0 = n * 128;
  int kbeg = ks * 1536;
  const short* Bp = W2T + (long)e * 768 * 3072;
  float* eo = ks ? e1 : e0;
  __shared__ __align__(16) short la[128*64], lb[128*64];
  int tid = threadIdx.x, w = tid >> 6, lane = tid & 63, l15 = lane & 15, quad = lane >> 4;
  int rl = lane >> 3, pch = lane & 7;
  long gA[4], gB[4];
  #pragma unroll
  for (int j = 0; j < 4; j++){
    int r = w*32 + j*8 + rl;
    int c = pch ^ (r & 7);
    gA[j] = (long)(M0 + r)*3072 + kbeg + c*8;
    gB[j] = (long)(N0 + r)*3072 + kbeg + c*8;
  }
  short* ldA = la + w*2048;
  short* ldB = lb + w*2048;
  f32x4 acc[4][4];
  #pragma unroll
  for (int i = 0; i < 4; i++)
    #pragma unroll
    for (int j = 0; j < 4; j++) acc[i][j] = (f32x4){0.f,0.f,0.f,0.f};
  int mbase = (w & 1) * 64, nbase = (w >> 1) * 64;
  for (int k0 = 0; k0 < 1536; k0 += 64){
    #pragma unroll
    for (int j = 0; j < 4; j++) gl_lds16(h1 + gA[j] + k0, ldA + j*512);
    #pragma unroll
    for (int j = 0; j < 4; j++) gl_lds16(Bp + gB[j] + k0, ldB + j*512);
    __syncthreads();
    #pragma unroll
    for (int kk = 0; kk < 2; kk++){
      int swq = ((kk*4 + quad) ^ (l15 & 7)) * 8;
      bf16x8 af[4];
      #pragma unroll
      for (int mt = 0; mt < 4; mt++)
        af[mt] = *(const bf16x8*)&la[(mbase+mt*16+l15)*64 + swq];
      #pragma unroll
      for (int nt = 0; nt < 4; nt++){
        bf16x8 bf = *(const bf16x8*)&lb[(nbase+nt*16+l15)*64 + swq];
        #pragma unroll
        for (int mt = 0; mt < 4; mt++) acc[mt][nt] = MFMA16(af[mt], bf, acc[mt][nt]);
      }
    }
    __syncthreads();
  }
  #pragma unroll
  for (int mt = 0; mt < 4; mt++)
    #pragma unroll
    for (int nt = 0; nt < 4; nt++)
      #pragma unroll
      for (int rg = 0; rg < 4; rg++){
        int ml = mbase + mt*16 + quad*4 + rg;
        int nn = N0 + nbase + nt*16 + l15;
        float vv = acc[mt][nt][rg] + (ks ? 0.f : b2[e*768 + nn]);
        eo[(long)(M0 + ml)*768 + nn] = vv;
      }
}

// ---------------- final combine: out = h + g0*(E0+E1)[s0] + g1*(E0+E1)[s1] --
__global__ void k_combine(const float* __restrict__ h,
                          const float* __restrict__ e0, const float* __restrict__ e1,
                          const int* __restrict__ inv, const float* __restrict__ gw,
                          float* __restrict__ out){
  int i = blockIdx.x * 256 + threadIdx.x;     // 393216 float4s
  int t = i / 192, c = i - t * 192;
  int s0 = inv[2*t], s1 = inv[2*t+1];
  float g0 = gw[2*t], g1 = gw[2*t+1];
  float4 a  = ((const float4*)h)[i];
  float4 x0 = ((const float4*)e0)[(long)s0*192 + c];
  float4 y0 = ((const float4*)e1)[(long)s0*192 + c];
  float4 x1 = ((const float4*)e0)[(long)s1*192 + c];
  float4 y1 = ((const float4*)e1)[(long)s1*192 + c];
  float4 o;
  o.x = a.x + g0*(x0.x + y0.x) + g1*(x1.x + y1.x);
  o.y = a.y + g0*(x0.y + y0.y) + g1*(x1.y + y1.y);
  o.z = a.z + g0*(x0.z + y0.z) + g1*(x1.z + y1.z);
  o.w = a.w + g0*(x0.w + y0.w) + g1*(x1.w + y1.w);
  ((float4*)out)[i] = o;
}

// ---------------- launcher ----------------
extern "C" void kernel_launch(void* const* d_in, const int* in_sizes, int n_in,
                              void* d_out, int out_size, void* d_ws, size_t ws_size,
                              hipStream_t stream){
  const float* x    = (const float*)d_in[0];
  const float* ln1g = (const float*)d_in[1];
  const float* ln1b = (const float*)d_in[2];
  const float* Wq   = (const float*)d_in[3];
  const float* Wk   = (const float*)d_in[4];
  const float* Wv   = (const float*)d_in[5];
  const float* Wo   = (const float*)d_in[6];
  const float* bo   = (const float*)d_in[7];
  const float* ln2g = (const float*)d_in[8];
  const float* ln2b = (const float*)d_in[9];
  const float* Wr   = (const float*)d_in[10];
  const float* br   = (const float*)d_in[11];
  const float* W1   = (const float*)d_in[12];
  const float* b1   = (const float*)d_in[13];
  const float* W2   = (const float*)d_in[14];
  const float* b2   = (const float*)d_in[15];

  char* ws = (char*)d_ws;
  size_t off = 0;
  auto alloc = [&](size_t bytes) -> void* {
    void* p = ws + off;
    off += (bytes + 255) & ~(size_t)255;
    return p;
  };
  short* WQKVH = (short*)alloc(2304l*768*2);
  short* WQKVL = (short*)alloc(2304l*768*2);
  short* WOH   = (short*)alloc(768l*768*2);
  short* WOL   = (short*)alloc(768l*768*2);
  short* W1T   = (short*)alloc(8l*3072*768*2);
  short* W2T   = (short*)alloc(8l*768*3072*2);
  short* XN1H  = (short*)alloc(2048l*768*2);
  short* XN1L  = (short*)alloc(2048l*768*2);
  short* QH    = (short*)alloc(2048l*768*2);
  short* QL    = (short*)alloc(2048l*768*2);
  short* KH    = (short*)alloc(2048l*768*2);
  short* KL    = (short*)alloc(2048l*768*2);
  short* VTH   = (short*)alloc(2048l*768*2);
  short* VTL   = (short*)alloc(2048l*768*2);
  short* ATH   = (short*)alloc(2048l*768*2);
  short* ATL   = (short*)alloc(2048l*768*2);
  float* HBUF  = (float*)alloc(2048l*768*4);
  short* XN2   = (short*)alloc(2048l*768*2);
  short* H1    = (short*)alloc(5120l*3072*2);
  float* E0    = (float*)alloc(5120l*768*4);
  float* E1    = (float*)alloc(5120l*768*4);
  float* PO    = (float*)alloc(2l*24*1024*64*4);
  float* PM    = (float*)alloc(2l*24*1024*4);
  float* PL    = (float*)alloc(2l*24*1024*4);
  int*   POFF  = (int*)alloc(8*4);
  int*   MBC   = (int*)alloc(8*4);
  int*   PTOT  = (int*)alloc(4);
  int*   SEL   = (int*)alloc(4096*4);
  int*   PPERM = (int*)alloc(5120*4);
  int*   INV   = (int*)alloc(4096*4);
  float* GW    = (float*)alloc(4096*4);
  (void)ws_size; (void)in_sizes; (void)n_in; (void)out_size;

  // weight prep (transpose + bf16 hi/lo split)
  k_transpose<<<dim3(24,24,1),256,0,stream>>>(Wq, 0, WQKVH,             WQKVL,             0, 768, 768);
  k_transpose<<<dim3(24,24,1),256,0,stream>>>(Wk, 0, WQKVH + 768l*768,  WQKVL + 768l*768,  0, 768, 768);
  k_transpose<<<dim3(24,24,1),256,0,stream>>>(Wv, 0, WQKVH + 1536l*768, WQKVL + 1536l*768, 0, 768, 768);
  k_transpose<<<dim3(24,24,1),256,0,stream>>>(Wo, 0, WOH, WOL, 0, 768, 768);
  k_transpose<<<dim3(96,24,8),256,0,stream>>>(W1, 768l*3072, W1T, nullptr, 3072l*768, 768, 3072);
  k_transpose<<<dim3(24,96,8),256,0,stream>>>(W2, 3072l*768, W2T, nullptr, 768l*3072, 3072, 768);

  // attention path (split-bf16 precision)
  k_ln1<<<2048,256,0,stream>>>(x, ln1g, ln1b, XN1H, XN1L);
  k_qkv<<<dim3(16,18),256,0,stream>>>(XN1H, XN1L, WQKVH, WQKVL, QH, QL, KH, KL, VTH, VTL);
  k_attn<<<dim3(32,24),256,0,stream>>>(QH, QL, KH, KL, VTH, VTL, PO, PM, PL);
  k_attn_combine<<<dim3(16,24),256,0,stream>>>(PO, PM, PL, ATH, ATL);
  k_wo<<<dim3(16,6),256,0,stream>>>(ATH, ATL, WOH, WOL, x, bo, HBUF);

  // router + MoE (no global atomics)
  k_ln2router<<<256,256,0,stream>>>(HBUF, ln2g, ln2b, Wr, br, XN2, SEL, GW);
  k_build<<<1,1024,0,stream>>>(SEL, POFF, MBC, PTOT, PPERM, INV);
  k_moe1<<<dim3(192,16),256,0,stream>>>(XN2, W1T, b1, POFF, MBC, PPERM, H1);
  k_moe2<<<dim3(96,16),256,0,stream>>>(H1, W2T, b2, POFF, MBC, E0, E1);
  k_combine<<<1536,256,0,stream>>>(HBUF, E0, E1, INV, GW, (float*)d_out);
}